// Round 14
// baseline (872.702 us; speedup 1.0000x reference)
//
#include <hip/hip_runtime.h>

#define DIM   256
#define NVEC  8192
#define NCODE 8192
#define DEPTH 4

#define KBLK  8                  // coarse k-splits; 1024 codes per block
#define KC    (NCODE / KBLK)
#define KT    (KC / 128)         // 8 code-tiles of 128 per block
#define FCAP  8192               // = NVEC: flag list can never overflow
#define FKS   32                 // fallback k-slices (256 codes each)
#define FV    8                  // fallback vectors per chunk
#define FCH   128                // fallback chunk-slots in grid
#define KAPPA 0.018f

typedef short  b8 __attribute__((ext_vector_type(8)));   // 8 bf16 raw
typedef short  b4 __attribute__((ext_vector_type(4)));
typedef float  f4 __attribute__((ext_vector_type(4)));

static __device__ __forceinline__ unsigned short f2bf(float f) {
  unsigned u = __float_as_uint(f);
  return (unsigned short)((u + 0x7FFFu + ((u >> 16) & 1u)) >> 16);  // RNE
}

static __device__ __forceinline__ void gll16(const void* g, void* l) {
  __builtin_amdgcn_global_load_lds(
      (const __attribute__((address_space(1))) void*)g,
      (__attribute__((address_space(3))) void*)l, 16, 0, 0);
}

// ---------------------------------------------------------------------------
// prep_norms: all-depth row norms: true ||c||^2 and bf16 ||ĉ||^2.
// ---------------------------------------------------------------------------
__global__ __launch_bounds__(256) void prep_norms(const float* __restrict__ cb_all,
                                                  float* __restrict__ cc,
                                                  float* __restrict__ cchat) {
  int row  = blockIdx.x * 4 + (threadIdx.x >> 6);
  int lane = threadIdx.x & 63;
  float4 v = *(const float4*)&cb_all[(size_t)row * DIM + lane * 4];
  float st = 0.f, sh = 0.f;
  float vv[4] = {v.x, v.y, v.z, v.w};
  #pragma unroll
  for (int j = 0; j < 4; ++j) {
    float hf = __uint_as_float(((unsigned)f2bf(vv[j])) << 16);
    st += vv[j] * vv[j];
    sh += hf * hf;
  }
  #pragma unroll
  for (int off = 32; off > 0; off >>= 1) {
    st += __shfl_down(st, off, 64);
    sh += __shfl_down(sh, off, 64);
  }
  if (lane == 0) { cc[row] = st; cchat[row] = sh; }
}

// ---------------------------------------------------------------------------
// prep_depth: codebook depth -> bf16 row-major (cbh) + f32 transposed (cbT).
// ---------------------------------------------------------------------------
__global__ __launch_bounds__(256) void prep_depth(const float* __restrict__ cbd,
                                                  unsigned short* __restrict__ cbh,
                                                  float* __restrict__ cbT) {
  __shared__ float ts[64][68];
  const int kb = blockIdx.x >> 2, db = blockIdx.x & 3;
  const int k0 = kb * 64, d0 = db * 64;
  const int t  = threadIdx.x;
  const int r  = t >> 2;
  const int c4 = (t & 3) * 16;

  const float* src = cbd + (size_t)(k0 + r) * DIM + d0 + c4;
  float4 q[4];
  #pragma unroll
  for (int i = 0; i < 4; ++i) q[i] = *(const float4*)(src + i * 4);

  b8 h0, h1;
  #pragma unroll
  for (int j = 0; j < 4; ++j) { h0[j] = (short)f2bf(q[0][j]); h0[4 + j] = (short)f2bf(q[1][j]); }
  #pragma unroll
  for (int j = 0; j < 4; ++j) { h1[j] = (short)f2bf(q[2][j]); h1[4 + j] = (short)f2bf(q[3][j]); }
  *(b8*)&cbh[(size_t)(k0 + r) * DIM + d0 + c4]     = h0;
  *(b8*)&cbh[(size_t)(k0 + r) * DIM + d0 + c4 + 8] = h1;

  #pragma unroll
  for (int i = 0; i < 4; ++i)
    #pragma unroll
    for (int j = 0; j < 4; ++j)
      ts[c4 + i * 4 + j][r] = q[i][j];
  __syncthreads();

  const int dd = t >> 2, kk4 = (t & 3) * 16;
  float* dst = cbT + (size_t)(d0 + dd) * NCODE + k0 + kk4;
  #pragma unroll
  for (int q4 = 0; q4 < 4; ++q4)
    *(float4*)(dst + q4 * 4) = *(const float4*)&ts[dd][kk4 + q4 * 4];
}

// ---------------------------------------------------------------------------
// init: resid = x (f32, in d_out), rb = bf16(x), rsum0 = ||x||^2.
// Block 0 also zeros fcount + done tickets (zint[0..127]).
// ---------------------------------------------------------------------------
__global__ __launch_bounds__(256) void init_kernel(const float* __restrict__ x,
                                                   float* __restrict__ resid,
                                                   unsigned short* __restrict__ rb,
                                                   float* __restrict__ rsum0,
                                                   int* __restrict__ zint) {
  if (blockIdx.x == 0 && threadIdx.x < 128) zint[threadIdx.x] = 0;
  int n    = blockIdx.x * 4 + (threadIdx.x >> 6);
  int lane = threadIdx.x & 63;
  float4 v = *(const float4*)&x[(size_t)n * DIM + lane * 4];
  *(float4*)&resid[(size_t)n * DIM + lane * 4] = v;
  b4 hv; hv[0] = (short)f2bf(v.x); hv[1] = (short)f2bf(v.y);
  hv[2] = (short)f2bf(v.z); hv[3] = (short)f2bf(v.w);
  *(b4*)&rb[(size_t)n * DIM + lane * 4] = hv;
  float s = v.x * v.x + v.y * v.y + v.z * v.z + v.w * v.w;
  #pragma unroll
  for (int off = 32; off > 0; off >>= 1) s += __shfl_down(s, off, 64);
  if (lane == 0) rsum0[n] = s;
}

// ---------------------------------------------------------------------------
// coarse: bf16 MFMA distance GEMM (R10 core, best measured 58us) + FUSED
// merge via last-block ticket: the 8th block finishing an mblk merges its
// 128 rows across KBLK partials (release: threadfence+atomic; acquire:
// threadfence after ticket), writes idx/flist/fslot, resets done[mblk].
// Fold uses med3 (v2' = med3(s,v1,v2), exact running-top-2 identity).
// 512 threads = 8 waves as 4x2 (mw,kw); wave tile 32x128; A-reg cache.
// grid = 64 mblk x KBLK (512 = exactly 2/CU); partials [kblk][n].
// ---------------------------------------------------------------------------
__global__ __launch_bounds__(512, 2) void coarse_kernel(
    const unsigned short* __restrict__ rb,
    const unsigned short* __restrict__ cbh,
    const float* __restrict__ cchat,
    float* __restrict__ pv1, int* __restrict__ pi1, float* __restrict__ pv2,
    const float* __restrict__ vnorm,
    int* __restrict__ idx, int* __restrict__ flist, int* __restrict__ fslot,
    int* __restrict__ fcount, int* __restrict__ done) {
  // layout: A0 @0, B0 @16384, A1 @32768, B1 @49152
  __shared__ __align__(16) char lds[65536];
  __shared__ int lastBlk;

  const int tid  = threadIdx.x;
  const int w    = tid >> 6;
  const int l    = tid & 63;
  const int mw   = w >> 1, kw = w & 1;          // 4 x 2 wave grid
  const int mblk = blockIdx.x / KBLK;
  const int kblk = blockIdx.x % KBLK;
  const int m0   = mblk * 128;
  const int K0   = kblk * KC;

  // staging offsets: 1024 chunks of 16B per tile, 2 per thread
  int aoff[2], boff[2], ldst[2];
  #pragma unroll
  for (int it = 0; it < 2; ++it) {
    int o = it * 512 + tid;
    int row = o >> 3, ssl = (o & 7) ^ (row & 7);
    aoff[it] = (m0 + row) * 512 + ssl * 16;        // bytes into rb
    boff[it] = (K0 + row) * 512 + ssl * 16;        // bytes into cbh (+kt*65536)
    ldst[it] = o * 16;
  }
  // fragment ds_read byte offsets (kk in {0,1} -> ^64)
  int offA[2][2], offB[4][2];
  #pragma unroll
  for (int mf = 0; mf < 2; ++mf) {
    int row = mw * 32 + mf * 16 + (l & 15);
    int base = row * 128 + (((l >> 4) ^ (row & 7)) * 16);
    offA[mf][0] = base; offA[mf][1] = base ^ 64;
  }
  #pragma unroll
  for (int nf = 0; nf < 4; ++nf) {
    int row = kw * 64 + nf * 16 + (l & 15);
    int base = row * 128 + (((l >> 4) ^ (row & 7)) * 16);
    offB[nf][0] = base; offB[nf][1] = base ^ 64;
  }

  const int kgb = K0 + kw * 64 + (l & 15);

  float tv1[8], tv2[8];
  int   ti1[8];
  #pragma unroll
  for (int s = 0; s < 8; ++s) { tv1[s] = 3.4e38f; tv2[s] = 3.4e38f; ti1[s] = 0; }

  f4 acc[2][4];
  b8 ar[4][2][2];                       // A cache [dt][kk][mf], 64 VGPR

  // prologue: stage (kt0, dt0) A+B into buf 0
  #pragma unroll
  for (int it = 0; it < 2; ++it) {
    gll16((const char*)rb  + aoff[it], lds + ldst[it]);
    gll16((const char*)cbh + boff[it], lds + 16384 + ldst[it]);
  }
  __syncthreads();

  for (int kt = 0; kt < KT; ++kt) {
    #pragma unroll
    for (int dt = 0; dt < 4; ++dt) {
      const int buf = dt & 1;           // compile-time
      // prefetch next stage into the alternate buffer
      if (!(kt == KT - 1 && dt == 3)) {
        const int ndt = (dt + 1) & 3;   // compile-time
        const int nb  = ndt & 1;
        const int nktoff = (dt == 3) ? (kt + 1) * 65536 : kt * 65536;
        if (kt == 0 && dt < 3) {        // A needed only for kt==0 stages
          #pragma unroll
          for (int it = 0; it < 2; ++it)
            gll16((const char*)rb + aoff[it] + ndt * 128,
                  lds + nb * 32768 + ldst[it]);
        }
        #pragma unroll
        for (int it = 0; it < 2; ++it)
          gll16((const char*)cbh + boff[it] + nktoff + ndt * 128,
                lds + nb * 32768 + 16384 + ldst[it]);
      }
      if (dt == 0) {
        #pragma unroll
        for (int i = 0; i < 2; ++i)
          #pragma unroll
          for (int j = 0; j < 4; ++j)
            acc[i][j] = (f4){0.f, 0.f, 0.f, 0.f};
      }
      #pragma unroll
      for (int kk = 0; kk < 2; ++kk) {
        b8 af[2], bb[4];
        if (kt == 0) {                  // load A frags from LDS, cache in regs
          #pragma unroll
          for (int mf = 0; mf < 2; ++mf) {
            af[mf] = *(const b8*)(lds + buf * 32768 + offA[mf][kk]);
            ar[dt][kk][mf] = af[mf];
          }
        } else {                        // reuse cached A frags
          #pragma unroll
          for (int mf = 0; mf < 2; ++mf) af[mf] = ar[dt][kk][mf];
        }
        #pragma unroll
        for (int nf = 0; nf < 4; ++nf)
          bb[nf] = *(const b8*)(lds + buf * 32768 + 16384 + offB[nf][kk]);
        #pragma unroll
        for (int mf = 0; mf < 2; ++mf)
          #pragma unroll
          for (int nf = 0; nf < 4; ++nf)
            acc[mf][nf] = __builtin_amdgcn_mfma_f32_16x16x32_bf16(
                af[mf], bb[nf], acc[mf][nf], 0, 0, 0);
      }
      if (dt == 3) {                    // fold tile kt into running top-2
        float cn[4]; int kg[4];
        #pragma unroll
        for (int nf = 0; nf < 4; ++nf) {
          kg[nf] = kgb + kt * 128 + nf * 16;
          cn[nf] = cchat[kg[nf]];
        }
        #pragma unroll
        for (int mf = 0; mf < 2; ++mf)
          #pragma unroll
          for (int r = 0; r < 4; ++r) {
            const int s0 = mf * 4 + r;
            #pragma unroll
            for (int nf = 0; nf < 4; ++nf) {
              float s = fmaf(-2.f, acc[mf][nf][r], cn[nf]);
              bool  c = s < tv1[s0];
              tv2[s0] = __builtin_amdgcn_fmed3f(s, tv1[s0], tv2[s0]);
              ti1[s0] = c ? kg[nf] : ti1[s0];
              tv1[s0] = fminf(tv1[s0], s);
            }
          }
      }
      __syncthreads();                  // drains vmcnt: next buffer ready
    }
  }

  // ---- single end-of-block reduction (alias lds as merge buffer) ----
  float* Mv1 = (float*)lds;             // [128][2]
  int*   Mi1 = (int*)(lds + 1024);
  float* Mv2 = (float*)(lds + 2048);

  #pragma unroll
  for (int s0 = 0; s0 < 8; ++s0) {
    float v1 = tv1[s0], v2 = tv2[s0];
    int   i1 = ti1[s0];
    #pragma unroll
    for (int m = 1; m < 16; m <<= 1) {
      float qv1 = __shfl_xor(v1, m);
      int   qi1 = __shfl_xor(i1, m);
      float qv2 = __shfl_xor(v2, m);
      bool  qw  = (qv1 < v1) || (qv1 == v1 && qi1 < i1);
      float lose = qw ? v1 : qv1;
      float wv2  = qw ? qv2 : v2;
      v2 = fminf(wv2, lose);
      if (qw) { v1 = qv1; i1 = qi1; }
    }
    if ((l & 15) == 0) {
      int mf = s0 >> 2, r = s0 & 3;
      int rowL = mw * 32 + mf * 16 + (l >> 4) * 4 + r;
      Mv1[rowL * 2 + kw] = v1; Mi1[rowL * 2 + kw] = i1; Mv2[rowL * 2 + kw] = v2;
    }
  }
  __syncthreads();
  if (tid < 128) {
    float a1 = Mv1[tid * 2],     a2 = Mv2[tid * 2];     int a1i = Mi1[tid * 2];
    float b1 = Mv1[tid * 2 + 1], b2 = Mv2[tid * 2 + 1]; int b1i = Mi1[tid * 2 + 1];
    bool  bw = (b1 < a1) || (b1 == a1 && b1i < a1i);
    float v1 = bw ? b1 : a1; int i1 = bw ? b1i : a1i;
    float v2 = fminf(bw ? b2 : a2, bw ? a1 : b1);
    int n = m0 + tid;
    pv1[kblk * NVEC + n] = v1;
    pi1[kblk * NVEC + n] = i1;
    pv2[kblk * NVEC + n] = v2;
  }

  // ---- fused merge: last block per mblk merges across KBLK ----
  __threadfence();                      // release own partial writes
  __syncthreads();                      // all threads' stores+fences done
  if (tid == 0)
    lastBlk = (atomicAdd(&done[mblk], 1) == KBLK - 1);
  __syncthreads();
  if (lastBlk) {
    __threadfence();                    // acquire other blocks' partials
    if (tid == 0) done[mblk] = 0;       // reset ticket for next launch
    if (tid < 128) {
      int n = m0 + tid;
      float v1 = 3.4e38f, v2 = 3.4e38f; int i1 = 0;
      #pragma unroll
      for (int kb = 0; kb < KBLK; ++kb) {
        float b1 = pv1[kb * NVEC + n]; int b1i = pi1[kb * NVEC + n];
        float b2 = pv2[kb * NVEC + n];
        bool  bw = (b1 < v1) || (b1 == v1 && b1i < i1);
        float lose = bw ? v1 : b1;
        float wv2  = bw ? b2 : v2;
        v2 = fminf(wv2, lose);
        if (bw) { v1 = b1; i1 = b1i; }
      }
      idx[n] = i1;
      float thr = KAPPA * sqrtf(fmaxf(v1 + vnorm[n], 0.f)) + 1e-5f;
      int slot = -1;
      if (v2 - v1 < thr) {
        slot = atomicAdd(fcount, 1);
        flist[slot] = n;
      }
      fslot[n] = slot;
    }
  }
}

// ---------------------------------------------------------------------------
// fb_scan_t: exact f32 rescan for flagged vectors, transposed codebook.
// chunk = FV(8) vectors; grid = FCH(128) chunk-slots x FKS = 4096 blocks
// (covers cnt <= 1024 without striding; grid-stride beyond).
// ---------------------------------------------------------------------------
__global__ __launch_bounds__(256, 4) void fb_scan_t(
    const float* __restrict__ cbT, const float* __restrict__ cc,
    const float* __restrict__ resid, const int* __restrict__ flist,
    const int* __restrict__ fcount,
    float* __restrict__ fpv, int* __restrict__ fpi) {
  __shared__ float vsT[DIM][FV + 4];       // 48B rows, f4-aligned
  __shared__ float mv[FV][4];
  __shared__ int   mi[FV][4];
  const int cnt = min(*fcount, FCAP);
  const int ks = blockIdx.x & (FKS - 1);
  const int t = threadIdx.x;
  const int w = t >> 6, l = t & 63;
  const int k = ks * 256 + t;
  const float cn = cc[k];

  for (int chunk = blockIdx.x >> 5; chunk * FV < cnt; chunk += FCH) {
    __syncthreads();
    #pragma unroll
    for (int v = 0; v < FV; ++v) {
      int s = chunk * FV + v;
      int n = flist[s < cnt ? s : chunk * FV];
      vsT[t][v] = resid[(size_t)n * DIM + t];
    }
    __syncthreads();

    float dot[FV];
    #pragma unroll
    for (int v = 0; v < FV; ++v) dot[v] = 0.f;

    #pragma unroll 8
    for (int d = 0; d < DIM; ++d) {
      float cv = cbT[(size_t)d * NCODE + k];
      f4 a0 = *(const f4*)&vsT[d][0];
      f4 a1 = *(const f4*)&vsT[d][4];
      dot[0] = fmaf(cv, a0[0], dot[0]);
      dot[1] = fmaf(cv, a0[1], dot[1]);
      dot[2] = fmaf(cv, a0[2], dot[2]);
      dot[3] = fmaf(cv, a0[3], dot[3]);
      dot[4] = fmaf(cv, a1[0], dot[4]);
      dot[5] = fmaf(cv, a1[1], dot[5]);
      dot[6] = fmaf(cv, a1[2], dot[6]);
      dot[7] = fmaf(cv, a1[3], dot[7]);
    }

    #pragma unroll
    for (int v = 0; v < FV; ++v) {
      float bv = fmaf(-2.f, dot[v], cn);
      int   bi = k;
      #pragma unroll
      for (int m = 1; m < 64; m <<= 1) {
        float qv = __shfl_xor(bv, m);
        int   qi = __shfl_xor(bi, m);
        if (qv < bv || (qv == bv && qi < bi)) { bv = qv; bi = qi; }
      }
      if (l == 0) { mv[v][w] = bv; mi[v][w] = bi; }
    }
    __syncthreads();
    if (t < FV) {
      float bv = mv[t][0]; int bi = mi[t][0];
      #pragma unroll
      for (int ww = 1; ww < 4; ++ww) {
        float qv = mv[t][ww]; int qi = mi[t][ww];
        if (qv < bv || (qv == bv && qi < bi)) { bv = qv; bi = qi; }
      }
      if (chunk * FV + t < cnt) {
        fpv[(size_t)(chunk * FV + t) * FKS + ks] = bv;
        fpi[(size_t)(chunk * FV + t) * FKS + ks] = bi;
      }
    }
  }
}

// ---------------------------------------------------------------------------
// update: final idx (inline fb-merge for flagged); resid -= cb[idx];
// rb = bf16(resid); rsum; code out as float. One wave per vector.
// Block 0 also re-zeros fcount for the next depth's fused merge.
// ---------------------------------------------------------------------------
__global__ __launch_bounds__(256) void update_kernel(
    const float* __restrict__ cb, const int* __restrict__ idx,
    const int* __restrict__ fslot,
    const float* __restrict__ fpv, const int* __restrict__ fpi,
    float* __restrict__ resid, unsigned short* __restrict__ rb,
    float* __restrict__ rsum_out, float* __restrict__ codes_out, int depth,
    int* __restrict__ fcount) {
  if (blockIdx.x == 0 && threadIdx.x == 0) *fcount = 0;
  int n    = blockIdx.x * 4 + (threadIdx.x >> 6);
  int lane = threadIdx.x & 63;
  int s    = fslot[n];                   // wave-uniform
  int bi;
  if (s >= 0) {
    float v = 3.4e38f; int ii = 0x7fffffff;
    if (lane < FKS) { v = fpv[(size_t)s * FKS + lane]; ii = fpi[(size_t)s * FKS + lane]; }
    #pragma unroll
    for (int m = 1; m < FKS; m <<= 1) {
      float qv = __shfl_xor(v, m);
      int   qi = __shfl_xor(ii, m);
      if (qv < v || (qv == v && qi < ii)) { v = qv; ii = qi; }
    }
    bi = __shfl(ii, 0, 64);
  } else {
    bi = idx[n];
  }
  float4 q = *(const float4*)&cb[(size_t)bi * DIM + lane * 4];
  float4 r = *(float4*)&resid[(size_t)n * DIM + lane * 4];
  r.x -= q.x; r.y -= q.y; r.z -= q.z; r.w -= q.w;
  *(float4*)&resid[(size_t)n * DIM + lane * 4] = r;
  b4 hv; hv[0] = (short)f2bf(r.x); hv[1] = (short)f2bf(r.y);
  hv[2] = (short)f2bf(r.z); hv[3] = (short)f2bf(r.w);
  *(b4*)&rb[(size_t)n * DIM + lane * 4] = hv;
  float s2 = r.x * r.x + r.y * r.y + r.z * r.z + r.w * r.w;
  #pragma unroll
  for (int off = 32; off > 0; off >>= 1) s2 += __shfl_down(s2, off, 64);
  if (lane == 0) {
    rsum_out[n] = s2;
    codes_out[n * DEPTH + depth] = (float)bi;
  }
}

// ---------------------------------------------------------------------------
// finalize: quants = x - resid (in place); block 0 reduces commitment loss.
// ---------------------------------------------------------------------------
__global__ __launch_bounds__(256) void finalize(const float* __restrict__ x,
                                                float* __restrict__ out,
                                                const float* __restrict__ rsumL) {
  int i = blockIdx.x * blockDim.x + threadIdx.x;
  float4 r  = *(float4*)&out[(size_t)i * 4];
  float4 xv = *(const float4*)&x[(size_t)i * 4];
  float4 o;
  o.x = xv.x - r.x; o.y = xv.y - r.y; o.z = xv.z - r.z; o.w = xv.w - r.w;
  *(float4*)&out[(size_t)i * 4] = o;

  if (blockIdx.x == 0) {
    __shared__ float sm[256];
    float s = 0.f;
    for (int j = threadIdx.x; j < DEPTH * NVEC; j += 256) s += rsumL[j];
    sm[threadIdx.x] = s;
    __syncthreads();
    for (int off = 128; off > 0; off >>= 1) {
      if (threadIdx.x < off) sm[threadIdx.x] += sm[threadIdx.x + off];
      __syncthreads();
    }
    if (threadIdx.x == 0)
      out[NVEC * DIM] = sm[0] / (float)DEPTH / (float)(NVEC * DIM);
  }
}

// ---------------------------------------------------------------------------
extern "C" void kernel_launch(void* const* d_in, const int* in_sizes, int n_in,
                              void* d_out, int out_size, void* d_ws, size_t ws_size,
                              hipStream_t stream) {
  const float* x  = (const float*)d_in[0];
  const float* cb = (const float*)d_in[1];
  float* out = (float*)d_out;
  char*  wsb = (char*)d_ws;

  // ws layout (~20 MB, under the proven 22.3 MB)
  unsigned short* cbh = (unsigned short*)(wsb);                 // 4 MB (per-depth)
  unsigned short* rb  = (unsigned short*)(wsb + 4194304);       // 4 MB
  float* cbT   = (float*)(wsb + 8388608);                       // 8 MB (per-depth)
  float* cc    = (float*)(wsb + 16777216);                      // 128 KB
  float* cchat = (float*)(wsb + 16908288);                      // 128 KB
  float* pv1   = (float*)(wsb + 17039360);                      // 512 KB
  int*   pi1   = (int*)  (wsb + 17563648);                      // 512 KB
  float* pv2   = (float*)(wsb + 18087936);                      // 512 KB
  float* rsum  = (float*)(wsb + 18612224);                      // 160 KB
  int*   idx   = (int*)  (wsb + 18776064);                      // 32 KB
  int*   flist = (int*)  (wsb + 18808832);                      // 32 KB
  int*   fslot = (int*)  (wsb + 18841600);                      // 32 KB
  int*   fcount= (int*)  (wsb + 18874368);                      // ticket page
  int*   done  = (int*)  (wsb + 18874368 + 256);                // 64 ints
  float* fpv   = (float*)(wsb + 18878464);                      // 1 MB
  int*   fpi   = (int*)  (wsb + 19927040);                      // 1 MB

  float* resid     = out;                    // quants region doubles as resid
  float* codes_out = out + NVEC * DIM + 1;

  prep_norms<<<(DEPTH * NCODE) / 4, 256, 0, stream>>>(cb, cc, cchat);
  init_kernel<<<NVEC / 4, 256, 0, stream>>>(x, resid, rb, rsum, fcount);

  for (int d = 0; d < DEPTH; ++d) {
    const size_t cbo = (size_t)d * NCODE * DIM;
    prep_depth<<<512, 256, 0, stream>>>(cb + cbo, cbh, cbT);
    coarse_kernel<<<(NVEC / 128) * KBLK, 512, 0, stream>>>(
        rb, cbh, cchat + d * NCODE, pv1, pi1, pv2,
        rsum + d * NVEC, idx, flist, fslot, fcount, done);
    fb_scan_t<<<FCH * FKS, 256, 0, stream>>>(
        cbT, cc + d * NCODE, resid, flist, fcount, fpv, fpi);
    update_kernel<<<NVEC / 4, 256, 0, stream>>>(
        cb + cbo, idx, fslot, fpv, fpi, resid, rb,
        rsum + (d + 1) * NVEC, codes_out, d, fcount);
  }
  finalize<<<(NVEC * DIM / 4) / 256, 256, 0, stream>>>(x, out, rsum + NVEC);
}

// Round 15
// 461.295 us; speedup vs baseline: 1.8919x; 1.8919x over previous
//
#include <hip/hip_runtime.h>

#define DIM   256
#define NVEC  8192
#define NCODE 8192
#define DEPTH 4

#define KBLK  8                  // coarse k-splits; 1024 codes per block
#define KC    (NCODE / KBLK)
#define KT    (KC / 128)         // 8 code-tiles of 128 per block
#define FCAP  8192               // = NVEC: flag list can never overflow
#define FKS   32                 // fallback k-slices (256 codes each)
#define FV    8                  // fallback vectors per chunk
#define FCH   128                // fallback chunk-slots in grid
#define KAPPA 0.018f

typedef short  b8 __attribute__((ext_vector_type(8)));   // 8 bf16 raw
typedef short  b4 __attribute__((ext_vector_type(4)));
typedef float  f4 __attribute__((ext_vector_type(4)));

static __device__ __forceinline__ unsigned short f2bf(float f) {
  unsigned u = __float_as_uint(f);
  return (unsigned short)((u + 0x7FFFu + ((u >> 16) & 1u)) >> 16);  // RNE
}

static __device__ __forceinline__ void gll16(const void* g, void* l) {
  __builtin_amdgcn_global_load_lds(
      (const __attribute__((address_space(1))) void*)g,
      (__attribute__((address_space(3))) void*)l, 16, 0, 0);
}

// ---------------------------------------------------------------------------
// prep_norms: all-depth row norms: true ||c||^2 and bf16 ||ĉ||^2.
// ---------------------------------------------------------------------------
__global__ __launch_bounds__(256) void prep_norms(const float* __restrict__ cb_all,
                                                  float* __restrict__ cc,
                                                  float* __restrict__ cchat) {
  int row  = blockIdx.x * 4 + (threadIdx.x >> 6);
  int lane = threadIdx.x & 63;
  float4 v = *(const float4*)&cb_all[(size_t)row * DIM + lane * 4];
  float st = 0.f, sh = 0.f;
  float vv[4] = {v.x, v.y, v.z, v.w};
  #pragma unroll
  for (int j = 0; j < 4; ++j) {
    float hf = __uint_as_float(((unsigned)f2bf(vv[j])) << 16);
    st += vv[j] * vv[j];
    sh += hf * hf;
  }
  #pragma unroll
  for (int off = 32; off > 0; off >>= 1) {
    st += __shfl_down(st, off, 64);
    sh += __shfl_down(sh, off, 64);
  }
  if (lane == 0) { cc[row] = st; cchat[row] = sh; }
}

// ---------------------------------------------------------------------------
// prep_depth: codebook depth -> bf16 row-major (cbh) + f32 transposed (cbT).
// ---------------------------------------------------------------------------
__global__ __launch_bounds__(256) void prep_depth(const float* __restrict__ cbd,
                                                  unsigned short* __restrict__ cbh,
                                                  float* __restrict__ cbT) {
  __shared__ float ts[64][68];
  const int kb = blockIdx.x >> 2, db = blockIdx.x & 3;
  const int k0 = kb * 64, d0 = db * 64;
  const int t  = threadIdx.x;
  const int r  = t >> 2;
  const int c4 = (t & 3) * 16;

  const float* src = cbd + (size_t)(k0 + r) * DIM + d0 + c4;
  float4 q[4];
  #pragma unroll
  for (int i = 0; i < 4; ++i) q[i] = *(const float4*)(src + i * 4);

  b8 h0, h1;
  #pragma unroll
  for (int j = 0; j < 4; ++j) { h0[j] = (short)f2bf(q[0][j]); h0[4 + j] = (short)f2bf(q[1][j]); }
  #pragma unroll
  for (int j = 0; j < 4; ++j) { h1[j] = (short)f2bf(q[2][j]); h1[4 + j] = (short)f2bf(q[3][j]); }
  *(b8*)&cbh[(size_t)(k0 + r) * DIM + d0 + c4]     = h0;
  *(b8*)&cbh[(size_t)(k0 + r) * DIM + d0 + c4 + 8] = h1;

  #pragma unroll
  for (int i = 0; i < 4; ++i)
    #pragma unroll
    for (int j = 0; j < 4; ++j)
      ts[c4 + i * 4 + j][r] = q[i][j];
  __syncthreads();

  const int dd = t >> 2, kk4 = (t & 3) * 16;
  float* dst = cbT + (size_t)(d0 + dd) * NCODE + k0 + kk4;
  #pragma unroll
  for (int q4 = 0; q4 < 4; ++q4)
    *(float4*)(dst + q4 * 4) = *(const float4*)&ts[dd][kk4 + q4 * 4];
}

// ---------------------------------------------------------------------------
// init: resid = x (f32, in d_out), rb = bf16(x), rsum0 = ||x||^2
// ---------------------------------------------------------------------------
__global__ __launch_bounds__(256) void init_kernel(const float* __restrict__ x,
                                                   float* __restrict__ resid,
                                                   unsigned short* __restrict__ rb,
                                                   float* __restrict__ rsum0) {
  int n    = blockIdx.x * 4 + (threadIdx.x >> 6);
  int lane = threadIdx.x & 63;
  float4 v = *(const float4*)&x[(size_t)n * DIM + lane * 4];
  *(float4*)&resid[(size_t)n * DIM + lane * 4] = v;
  b4 hv; hv[0] = (short)f2bf(v.x); hv[1] = (short)f2bf(v.y);
  hv[2] = (short)f2bf(v.z); hv[3] = (short)f2bf(v.w);
  *(b4*)&rb[(size_t)n * DIM + lane * 4] = hv;
  float s = v.x * v.x + v.y * v.y + v.z * v.z + v.w * v.w;
  #pragma unroll
  for (int off = 32; off > 0; off >>= 1) s += __shfl_down(s, off, 64);
  if (lane == 0) rsum0[n] = s;
}

// ---------------------------------------------------------------------------
// coarse: bf16 MFMA distance GEMM, double-buffered 2-phase pipeline (R13
// verbatim — best measured 58us, VGPR 84, no spill) + med3 fold (validated
// R14: tv2' = med3(s,tv1,tv2) is the exact running-top-2 second-min).
// NO fused merge: R14's __threadfence per block cost 3x (cross-XCD L2
// writeback); the kernel-launch boundary provides visibility for free.
// A-register cache: A staged+ds_read only during kt==0, then 16 b8 regs.
// launch_bounds (512,2): 256-VGPR cap — (512,4)'s 128 cap spills ar (R9).
// 512 threads = 8 waves as 4x2 (mw,kw); wave tile 32x128.
// grid = 64 mblk x KBLK (512 = exactly 2/CU); partials [kblk][n].
// ---------------------------------------------------------------------------
__global__ __launch_bounds__(512, 2) void coarse_kernel(
    const unsigned short* __restrict__ rb,
    const unsigned short* __restrict__ cbh,
    const float* __restrict__ cchat,
    float* __restrict__ pv1, int* __restrict__ pi1, float* __restrict__ pv2,
    int* __restrict__ fcount) {
  // layout: A0 @0, B0 @16384, A1 @32768, B1 @49152
  __shared__ __align__(16) char lds[65536];

  const int tid  = threadIdx.x;
  const int w    = tid >> 6;
  const int l    = tid & 63;
  const int mw   = w >> 1, kw = w & 1;          // 4 x 2 wave grid
  const int mblk = blockIdx.x / KBLK;
  const int kblk = blockIdx.x % KBLK;
  const int m0   = mblk * 128;
  const int K0   = kblk * KC;

  if (blockIdx.x == 0 && tid == 0) *fcount = 0;   // merge runs after: race-free

  // staging offsets: 1024 chunks of 16B per tile, 2 per thread
  int aoff[2], boff[2], ldst[2];
  #pragma unroll
  for (int it = 0; it < 2; ++it) {
    int o = it * 512 + tid;
    int row = o >> 3, ssl = (o & 7) ^ (row & 7);
    aoff[it] = (m0 + row) * 512 + ssl * 16;        // bytes into rb
    boff[it] = (K0 + row) * 512 + ssl * 16;        // bytes into cbh (+kt*65536)
    ldst[it] = o * 16;
  }
  // fragment ds_read byte offsets (kk in {0,1} -> ^64)
  int offA[2][2], offB[4][2];
  #pragma unroll
  for (int mf = 0; mf < 2; ++mf) {
    int row = mw * 32 + mf * 16 + (l & 15);
    int base = row * 128 + (((l >> 4) ^ (row & 7)) * 16);
    offA[mf][0] = base; offA[mf][1] = base ^ 64;
  }
  #pragma unroll
  for (int nf = 0; nf < 4; ++nf) {
    int row = kw * 64 + nf * 16 + (l & 15);
    int base = row * 128 + (((l >> 4) ^ (row & 7)) * 16);
    offB[nf][0] = base; offB[nf][1] = base ^ 64;
  }

  const int kgb = K0 + kw * 64 + (l & 15);

  float tv1[8], tv2[8];
  int   ti1[8];
  #pragma unroll
  for (int s = 0; s < 8; ++s) { tv1[s] = 3.4e38f; tv2[s] = 3.4e38f; ti1[s] = 0; }

  f4 acc[2][4];
  b8 ar[4][2][2];                       // A cache [dt][kk][mf], 64 VGPR

  // prologue: stage (kt0, dt0) A+B into buf 0
  #pragma unroll
  for (int it = 0; it < 2; ++it) {
    gll16((const char*)rb  + aoff[it], lds + ldst[it]);
    gll16((const char*)cbh + boff[it], lds + 16384 + ldst[it]);
  }
  __syncthreads();

  for (int kt = 0; kt < KT; ++kt) {
    #pragma unroll
    for (int dt = 0; dt < 4; ++dt) {
      const int buf = dt & 1;           // compile-time
      // prefetch next stage into the alternate buffer
      if (!(kt == KT - 1 && dt == 3)) {
        const int ndt = (dt + 1) & 3;   // compile-time
        const int nb  = ndt & 1;
        const int nktoff = (dt == 3) ? (kt + 1) * 65536 : kt * 65536;
        if (kt == 0 && dt < 3) {        // A needed only for kt==0 stages
          #pragma unroll
          for (int it = 0; it < 2; ++it)
            gll16((const char*)rb + aoff[it] + ndt * 128,
                  lds + nb * 32768 + ldst[it]);
        }
        #pragma unroll
        for (int it = 0; it < 2; ++it)
          gll16((const char*)cbh + boff[it] + nktoff + ndt * 128,
                lds + nb * 32768 + 16384 + ldst[it]);
      }
      if (dt == 0) {
        #pragma unroll
        for (int i = 0; i < 2; ++i)
          #pragma unroll
          for (int j = 0; j < 4; ++j)
            acc[i][j] = (f4){0.f, 0.f, 0.f, 0.f};
      }
      #pragma unroll
      for (int kk = 0; kk < 2; ++kk) {
        b8 af[2], bb[4];
        if (kt == 0) {                  // load A frags from LDS, cache in regs
          #pragma unroll
          for (int mf = 0; mf < 2; ++mf) {
            af[mf] = *(const b8*)(lds + buf * 32768 + offA[mf][kk]);
            ar[dt][kk][mf] = af[mf];
          }
        } else {                        // reuse cached A frags
          #pragma unroll
          for (int mf = 0; mf < 2; ++mf) af[mf] = ar[dt][kk][mf];
        }
        #pragma unroll
        for (int nf = 0; nf < 4; ++nf)
          bb[nf] = *(const b8*)(lds + buf * 32768 + 16384 + offB[nf][kk]);
        #pragma unroll
        for (int mf = 0; mf < 2; ++mf)
          #pragma unroll
          for (int nf = 0; nf < 4; ++nf)
            acc[mf][nf] = __builtin_amdgcn_mfma_f32_16x16x32_bf16(
                af[mf], bb[nf], acc[mf][nf], 0, 0, 0);
      }
      if (dt == 3) {                    // fold tile kt into running top-2
        float cn[4]; int kg[4];
        #pragma unroll
        for (int nf = 0; nf < 4; ++nf) {
          kg[nf] = kgb + kt * 128 + nf * 16;
          cn[nf] = cchat[kg[nf]];
        }
        #pragma unroll
        for (int mf = 0; mf < 2; ++mf)
          #pragma unroll
          for (int r = 0; r < 4; ++r) {
            const int s0 = mf * 4 + r;
            #pragma unroll
            for (int nf = 0; nf < 4; ++nf) {
              float s = fmaf(-2.f, acc[mf][nf][r], cn[nf]);
              bool  c = s < tv1[s0];
              tv2[s0] = __builtin_amdgcn_fmed3f(s, tv1[s0], tv2[s0]);
              ti1[s0] = c ? kg[nf] : ti1[s0];
              tv1[s0] = fminf(tv1[s0], s);
            }
          }
      }
      __syncthreads();                  // drains vmcnt: next buffer ready
    }
  }

  // ---- single end-of-block reduction (alias lds as merge buffer) ----
  float* Mv1 = (float*)lds;             // [128][2]
  int*   Mi1 = (int*)(lds + 1024);
  float* Mv2 = (float*)(lds + 2048);

  #pragma unroll
  for (int s0 = 0; s0 < 8; ++s0) {
    float v1 = tv1[s0], v2 = tv2[s0];
    int   i1 = ti1[s0];
    #pragma unroll
    for (int m = 1; m < 16; m <<= 1) {
      float qv1 = __shfl_xor(v1, m);
      int   qi1 = __shfl_xor(i1, m);
      float qv2 = __shfl_xor(v2, m);
      bool  qw  = (qv1 < v1) || (qv1 == v1 && qi1 < i1);
      float lose = qw ? v1 : qv1;
      float wv2  = qw ? qv2 : v2;
      v2 = fminf(wv2, lose);
      if (qw) { v1 = qv1; i1 = qi1; }
    }
    if ((l & 15) == 0) {
      int mf = s0 >> 2, r = s0 & 3;
      int rowL = mw * 32 + mf * 16 + (l >> 4) * 4 + r;
      Mv1[rowL * 2 + kw] = v1; Mi1[rowL * 2 + kw] = i1; Mv2[rowL * 2 + kw] = v2;
    }
  }
  __syncthreads();
  if (tid < 128) {
    float a1 = Mv1[tid * 2],     a2 = Mv2[tid * 2];     int a1i = Mi1[tid * 2];
    float b1 = Mv1[tid * 2 + 1], b2 = Mv2[tid * 2 + 1]; int b1i = Mi1[tid * 2 + 1];
    bool  bw = (b1 < a1) || (b1 == a1 && b1i < a1i);
    float v1 = bw ? b1 : a1; int i1 = bw ? b1i : a1i;
    float v2 = fminf(bw ? b2 : a2, bw ? a1 : b1);
    int n = m0 + tid;
    pv1[kblk * NVEC + n] = v1;
    pi1[kblk * NVEC + n] = i1;
    pv2[kblk * NVEC + n] = v2;
  }
}

// ---------------------------------------------------------------------------
// merge: global top2 over KBLK partials; provisional idx; flag near-ties.
// ---------------------------------------------------------------------------
__global__ __launch_bounds__(256) void merge_kernel(
    const float* __restrict__ pv1, const int* __restrict__ pi1,
    const float* __restrict__ pv2, const float* __restrict__ vnorm,
    int* __restrict__ idx, int* __restrict__ flist, int* __restrict__ fslot,
    int* __restrict__ fcount) {
  int n = blockIdx.x * 256 + threadIdx.x;
  float v1 = 3.4e38f, v2 = 3.4e38f; int i1 = 0;
  #pragma unroll
  for (int kb = 0; kb < KBLK; ++kb) {
    float b1 = pv1[kb * NVEC + n]; int b1i = pi1[kb * NVEC + n];
    float b2 = pv2[kb * NVEC + n];
    bool  bw = (b1 < v1) || (b1 == v1 && b1i < i1);
    float lose = bw ? v1 : b1;
    float wv2  = bw ? b2 : v2;
    v2 = fminf(wv2, lose);
    if (bw) { v1 = b1; i1 = b1i; }
  }
  idx[n] = i1;
  float thr = KAPPA * sqrtf(fmaxf(v1 + vnorm[n], 0.f)) + 1e-5f;
  int slot = -1;
  if (v2 - v1 < thr) {
    slot = atomicAdd(fcount, 1);
    flist[slot] = n;
  }
  fslot[n] = slot;
}

// ---------------------------------------------------------------------------
// fb_scan_t: exact f32 rescan for flagged vectors, transposed codebook.
// chunk = FV(8) vectors; grid = FCH(128) chunk-slots x FKS = 4096 blocks
// (covers cnt <= 1024 without striding; grid-stride beyond).
// ---------------------------------------------------------------------------
__global__ __launch_bounds__(256, 4) void fb_scan_t(
    const float* __restrict__ cbT, const float* __restrict__ cc,
    const float* __restrict__ resid, const int* __restrict__ flist,
    const int* __restrict__ fcount,
    float* __restrict__ fpv, int* __restrict__ fpi) {
  __shared__ float vsT[DIM][FV + 4];       // 48B rows, f4-aligned
  __shared__ float mv[FV][4];
  __shared__ int   mi[FV][4];
  const int cnt = min(*fcount, FCAP);
  const int ks = blockIdx.x & (FKS - 1);
  const int t = threadIdx.x;
  const int w = t >> 6, l = t & 63;
  const int k = ks * 256 + t;
  const float cn = cc[k];

  for (int chunk = blockIdx.x >> 5; chunk * FV < cnt; chunk += FCH) {
    __syncthreads();
    #pragma unroll
    for (int v = 0; v < FV; ++v) {
      int s = chunk * FV + v;
      int n = flist[s < cnt ? s : chunk * FV];
      vsT[t][v] = resid[(size_t)n * DIM + t];
    }
    __syncthreads();

    float dot[FV];
    #pragma unroll
    for (int v = 0; v < FV; ++v) dot[v] = 0.f;

    #pragma unroll 8
    for (int d = 0; d < DIM; ++d) {
      float cv = cbT[(size_t)d * NCODE + k];
      f4 a0 = *(const f4*)&vsT[d][0];
      f4 a1 = *(const f4*)&vsT[d][4];
      dot[0] = fmaf(cv, a0[0], dot[0]);
      dot[1] = fmaf(cv, a0[1], dot[1]);
      dot[2] = fmaf(cv, a0[2], dot[2]);
      dot[3] = fmaf(cv, a0[3], dot[3]);
      dot[4] = fmaf(cv, a1[0], dot[4]);
      dot[5] = fmaf(cv, a1[1], dot[5]);
      dot[6] = fmaf(cv, a1[2], dot[6]);
      dot[7] = fmaf(cv, a1[3], dot[7]);
    }

    #pragma unroll
    for (int v = 0; v < FV; ++v) {
      float bv = fmaf(-2.f, dot[v], cn);
      int   bi = k;
      #pragma unroll
      for (int m = 1; m < 64; m <<= 1) {
        float qv = __shfl_xor(bv, m);
        int   qi = __shfl_xor(bi, m);
        if (qv < bv || (qv == bv && qi < bi)) { bv = qv; bi = qi; }
      }
      if (l == 0) { mv[v][w] = bv; mi[v][w] = bi; }
    }
    __syncthreads();
    if (t < FV) {
      float bv = mv[t][0]; int bi = mi[t][0];
      #pragma unroll
      for (int ww = 1; ww < 4; ++ww) {
        float qv = mv[t][ww]; int qi = mi[t][ww];
        if (qv < bv || (qv == bv && qi < bi)) { bv = qv; bi = qi; }
      }
      if (chunk * FV + t < cnt) {
        fpv[(size_t)(chunk * FV + t) * FKS + ks] = bv;
        fpi[(size_t)(chunk * FV + t) * FKS + ks] = bi;
      }
    }
  }
}

// ---------------------------------------------------------------------------
// update: final idx (inline fb-merge for flagged); resid -= cb[idx];
// rb = bf16(resid); rsum; code out as float. One wave per vector.
// ---------------------------------------------------------------------------
__global__ __launch_bounds__(256) void update_kernel(
    const float* __restrict__ cb, const int* __restrict__ idx,
    const int* __restrict__ fslot,
    const float* __restrict__ fpv, const int* __restrict__ fpi,
    float* __restrict__ resid, unsigned short* __restrict__ rb,
    float* __restrict__ rsum_out, float* __restrict__ codes_out, int depth) {
  int n    = blockIdx.x * 4 + (threadIdx.x >> 6);
  int lane = threadIdx.x & 63;
  int s    = fslot[n];                   // wave-uniform
  int bi;
  if (s >= 0) {
    float v = 3.4e38f; int ii = 0x7fffffff;
    if (lane < FKS) { v = fpv[(size_t)s * FKS + lane]; ii = fpi[(size_t)s * FKS + lane]; }
    #pragma unroll
    for (int m = 1; m < FKS; m <<= 1) {
      float qv = __shfl_xor(v, m);
      int   qi = __shfl_xor(ii, m);
      if (qv < v || (qv == v && qi < ii)) { v = qv; ii = qi; }
    }
    bi = __shfl(ii, 0, 64);
  } else {
    bi = idx[n];
  }
  float4 q = *(const float4*)&cb[(size_t)bi * DIM + lane * 4];
  float4 r = *(float4*)&resid[(size_t)n * DIM + lane * 4];
  r.x -= q.x; r.y -= q.y; r.z -= q.z; r.w -= q.w;
  *(float4*)&resid[(size_t)n * DIM + lane * 4] = r;
  b4 hv; hv[0] = (short)f2bf(r.x); hv[1] = (short)f2bf(r.y);
  hv[2] = (short)f2bf(r.z); hv[3] = (short)f2bf(r.w);
  *(b4*)&rb[(size_t)n * DIM + lane * 4] = hv;
  float s2 = r.x * r.x + r.y * r.y + r.z * r.z + r.w * r.w;
  #pragma unroll
  for (int off = 32; off > 0; off >>= 1) s2 += __shfl_down(s2, off, 64);
  if (lane == 0) {
    rsum_out[n] = s2;
    codes_out[n * DEPTH + depth] = (float)bi;
  }
}

// ---------------------------------------------------------------------------
// finalize: quants = x - resid (in place); block 0 reduces commitment loss.
// ---------------------------------------------------------------------------
__global__ __launch_bounds__(256) void finalize(const float* __restrict__ x,
                                                float* __restrict__ out,
                                                const float* __restrict__ rsumL) {
  int i = blockIdx.x * blockDim.x + threadIdx.x;
  float4 r  = *(float4*)&out[(size_t)i * 4];
  float4 xv = *(const float4*)&x[(size_t)i * 4];
  float4 o;
  o.x = xv.x - r.x; o.y = xv.y - r.y; o.z = xv.z - r.z; o.w = xv.w - r.w;
  *(float4*)&out[(size_t)i * 4] = o;

  if (blockIdx.x == 0) {
    __shared__ float sm[256];
    float s = 0.f;
    for (int j = threadIdx.x; j < DEPTH * NVEC; j += 256) s += rsumL[j];
    sm[threadIdx.x] = s;
    __syncthreads();
    for (int off = 128; off > 0; off >>= 1) {
      if (threadIdx.x < off) sm[threadIdx.x] += sm[threadIdx.x + off];
      __syncthreads();
    }
    if (threadIdx.x == 0)
      out[NVEC * DIM] = sm[0] / (float)DEPTH / (float)(NVEC * DIM);
  }
}

// ---------------------------------------------------------------------------
extern "C" void kernel_launch(void* const* d_in, const int* in_sizes, int n_in,
                              void* d_out, int out_size, void* d_ws, size_t ws_size,
                              hipStream_t stream) {
  const float* x  = (const float*)d_in[0];
  const float* cb = (const float*)d_in[1];
  float* out = (float*)d_out;
  char*  wsb = (char*)d_ws;

  // ws layout (~20 MB, under the proven 22.3 MB)
  unsigned short* cbh = (unsigned short*)(wsb);                 // 4 MB (per-depth)
  unsigned short* rb  = (unsigned short*)(wsb + 4194304);       // 4 MB
  float* cbT   = (float*)(wsb + 8388608);                       // 8 MB (per-depth)
  float* cc    = (float*)(wsb + 16777216);                      // 128 KB
  float* cchat = (float*)(wsb + 16908288);                      // 128 KB
  float* pv1   = (float*)(wsb + 17039360);                      // 512 KB
  int*   pi1   = (int*)  (wsb + 17563648);                      // 512 KB
  float* pv2   = (float*)(wsb + 18087936);                      // 512 KB
  float* rsum  = (float*)(wsb + 18612224);                      // 160 KB
  int*   idx   = (int*)  (wsb + 18776064);                      // 32 KB
  int*   flist = (int*)  (wsb + 18808832);                      // 32 KB
  int*   fslot = (int*)  (wsb + 18841600);                      // 32 KB
  int*   fcount= (int*)  (wsb + 18874368);                      // 4 KB pad
  float* fpv   = (float*)(wsb + 18878464);                      // 1 MB
  int*   fpi   = (int*)  (wsb + 19927040);                      // 1 MB

  float* resid     = out;                    // quants region doubles as resid
  float* codes_out = out + NVEC * DIM + 1;

  prep_norms<<<(DEPTH * NCODE) / 4, 256, 0, stream>>>(cb, cc, cchat);
  init_kernel<<<NVEC / 4, 256, 0, stream>>>(x, resid, rb, rsum);

  for (int d = 0; d < DEPTH; ++d) {
    const size_t cbo = (size_t)d * NCODE * DIM;
    prep_depth<<<512, 256, 0, stream>>>(cb + cbo, cbh, cbT);
    coarse_kernel<<<(NVEC / 128) * KBLK, 512, 0, stream>>>(
        rb, cbh, cchat + d * NCODE, pv1, pi1, pv2, fcount);
    merge_kernel<<<NVEC / 256, 256, 0, stream>>>(
        pv1, pi1, pv2, rsum + d * NVEC, idx, flist, fslot, fcount);
    fb_scan_t<<<FCH * FKS, 256, 0, stream>>>(
        cbT, cc + d * NCODE, resid, flist, fcount, fpv, fpi);
    update_kernel<<<NVEC / 4, 256, 0, stream>>>(
        cb + cbo, idx, fslot, fpv, fpi, resid, rb,
        rsum + (d + 1) * NVEC, codes_out, d);
  }
  finalize<<<(NVEC * DIM / 4) / 256, 256, 0, stream>>>(x, out, rsum + NVEC);
}

// Round 16
// 447.430 us; speedup vs baseline: 1.9505x; 1.0310x over previous
//
#include <hip/hip_runtime.h>

#define DIM   256
#define NVEC  8192
#define NCODE 8192
#define DEPTH 4

#define KBLK  8                  // coarse k-splits; 1024 codes per block
#define KC    (NCODE / KBLK)
#define KT    (KC / 128)         // 8 code-tiles of 128 per block
#define FCAP  8192               // = NVEC: flag list can never overflow
#define FKS   32                 // fallback k-slices (256 codes each)
#define FV    8                  // fallback vectors per chunk
#define FCH   128                // fallback chunk-slots in grid
#define KAPPA 0.018f

typedef short  b8 __attribute__((ext_vector_type(8)));   // 8 bf16 raw
typedef short  b4 __attribute__((ext_vector_type(4)));
typedef float  f4 __attribute__((ext_vector_type(4)));

static __device__ __forceinline__ unsigned short f2bf(float f) {
  unsigned u = __float_as_uint(f);
  return (unsigned short)((u + 0x7FFFu + ((u >> 16) & 1u)) >> 16);  // RNE
}

static __device__ __forceinline__ void gll16(const void* g, void* l) {
  __builtin_amdgcn_global_load_lds(
      (const __attribute__((address_space(1))) void*)g,
      (__attribute__((address_space(3))) void*)l, 16, 0, 0);
}

// ---------------------------------------------------------------------------
// prep_norms: all-depth row norms: true ||c||^2 and bf16 ||ĉ||^2.
// ---------------------------------------------------------------------------
__global__ __launch_bounds__(256) void prep_norms(const float* __restrict__ cb_all,
                                                  float* __restrict__ cc,
                                                  float* __restrict__ cchat) {
  int row  = blockIdx.x * 4 + (threadIdx.x >> 6);
  int lane = threadIdx.x & 63;
  float4 v = *(const float4*)&cb_all[(size_t)row * DIM + lane * 4];
  float st = 0.f, sh = 0.f;
  float vv[4] = {v.x, v.y, v.z, v.w};
  #pragma unroll
  for (int j = 0; j < 4; ++j) {
    float hf = __uint_as_float(((unsigned)f2bf(vv[j])) << 16);
    st += vv[j] * vv[j];
    sh += hf * hf;
  }
  #pragma unroll
  for (int off = 32; off > 0; off >>= 1) {
    st += __shfl_down(st, off, 64);
    sh += __shfl_down(sh, off, 64);
  }
  if (lane == 0) { cc[row] = st; cchat[row] = sh; }
}

// ---------------------------------------------------------------------------
// prep_depth: codebook depth -> bf16 row-major (cbh) + f32 transposed (cbT).
// ---------------------------------------------------------------------------
__global__ __launch_bounds__(256) void prep_depth(const float* __restrict__ cbd,
                                                  unsigned short* __restrict__ cbh,
                                                  float* __restrict__ cbT) {
  __shared__ float ts[64][68];
  const int kb = blockIdx.x >> 2, db = blockIdx.x & 3;
  const int k0 = kb * 64, d0 = db * 64;
  const int t  = threadIdx.x;
  const int r  = t >> 2;
  const int c4 = (t & 3) * 16;

  const float* src = cbd + (size_t)(k0 + r) * DIM + d0 + c4;
  float4 q[4];
  #pragma unroll
  for (int i = 0; i < 4; ++i) q[i] = *(const float4*)(src + i * 4);

  b8 h0, h1;
  #pragma unroll
  for (int j = 0; j < 4; ++j) { h0[j] = (short)f2bf(q[0][j]); h0[4 + j] = (short)f2bf(q[1][j]); }
  #pragma unroll
  for (int j = 0; j < 4; ++j) { h1[j] = (short)f2bf(q[2][j]); h1[4 + j] = (short)f2bf(q[3][j]); }
  *(b8*)&cbh[(size_t)(k0 + r) * DIM + d0 + c4]     = h0;
  *(b8*)&cbh[(size_t)(k0 + r) * DIM + d0 + c4 + 8] = h1;

  #pragma unroll
  for (int i = 0; i < 4; ++i)
    #pragma unroll
    for (int j = 0; j < 4; ++j)
      ts[c4 + i * 4 + j][r] = q[i][j];
  __syncthreads();

  const int dd = t >> 2, kk4 = (t & 3) * 16;
  float* dst = cbT + (size_t)(d0 + dd) * NCODE + k0 + kk4;
  #pragma unroll
  for (int q4 = 0; q4 < 4; ++q4)
    *(float4*)(dst + q4 * 4) = *(const float4*)&ts[dd][kk4 + q4 * 4];
}

// ---------------------------------------------------------------------------
// init: resid = x (f32, in d_out), rb = bf16(x), rsum0 = ||x||^2
// ---------------------------------------------------------------------------
__global__ __launch_bounds__(256) void init_kernel(const float* __restrict__ x,
                                                   float* __restrict__ resid,
                                                   unsigned short* __restrict__ rb,
                                                   float* __restrict__ rsum0) {
  int n    = blockIdx.x * 4 + (threadIdx.x >> 6);
  int lane = threadIdx.x & 63;
  float4 v = *(const float4*)&x[(size_t)n * DIM + lane * 4];
  *(float4*)&resid[(size_t)n * DIM + lane * 4] = v;
  b4 hv; hv[0] = (short)f2bf(v.x); hv[1] = (short)f2bf(v.y);
  hv[2] = (short)f2bf(v.z); hv[3] = (short)f2bf(v.w);
  *(b4*)&rb[(size_t)n * DIM + lane * 4] = hv;
  float s = v.x * v.x + v.y * v.y + v.z * v.z + v.w * v.w;
  #pragma unroll
  for (int off = 32; off > 0; off >>= 1) s += __shfl_down(s, off, 64);
  if (lane == 0) rsum0[n] = s;
}

// ---------------------------------------------------------------------------
// coarse: bf16 MFMA distance GEMM — fine-interleaved counted-vmcnt pipeline
// (template window discipline; math/fold identical to R15's proven kernel).
// 4x16KB B ring buffers, depth-2 gll16 prefetch, vmcnt(2) counted waits
// (never 0 mid-loop), raw s_barrier (no implicit drain), sched_barrier
// fences (rule #18). Window p: ds_read frags(p) | issue g(p+2) | vmcnt(2)
// [ensures g(p+1)] | s_barrier | lgkmcnt(0) | setprio+16 MFMA | fold@dt3.
// Buffer-overwrite audit: g(p+2) targets buf[(p-2)%4], whose reads were
// lgkm-complete at window p-2 step-e, before the window p-1 barrier.
// A: one-time direct global->reg preload (R11-proven; swizzle cancels).
// cchat slice in LDS @64KB so fold never perturbs the vmcnt FIFO.
// 512 threads = 8 waves as 4x2 (mw,kw); wave tile 32x128.
// grid = 64 mblk x KBLK (512 = 2/CU); partials [kblk][n].
// ---------------------------------------------------------------------------
__global__ __launch_bounds__(512, 2) void coarse_kernel(
    const unsigned short* __restrict__ rb,
    const unsigned short* __restrict__ cbh,
    const float* __restrict__ cchat,
    float* __restrict__ pv1, int* __restrict__ pi1, float* __restrict__ pv2,
    int* __restrict__ fcount) {
  // B0 @0, B1 @16K, B2 @32K, B3 @48K, cchat @64K (4KB)
  __shared__ __align__(16) char lds[69632];

  const int tid  = threadIdx.x;
  const int w    = tid >> 6;
  const int l    = tid & 63;
  const int mw   = w >> 1, kw = w & 1;          // 4 x 2 wave grid
  const int mblk = blockIdx.x / KBLK;
  const int kblk = blockIdx.x % KBLK;
  const int m0   = mblk * 128;
  const int K0   = kblk * KC;

  if (blockIdx.x == 0 && tid == 0) *fcount = 0;   // merge runs after: race-free

  // B staging: 1024 chunks of 16B per stage, 2 per thread
  int boff[2], ldst[2];
  #pragma unroll
  for (int it = 0; it < 2; ++it) {
    int o = it * 512 + tid;
    int row = o >> 3, ssl = (o & 7) ^ (row & 7);
    boff[it] = (K0 + row) * 512 + ssl * 16;        // bytes into cbh (+stage*128/65536)
    ldst[it] = o * 16;
  }
  // B fragment ds_read byte offsets (kk in {0,1} -> ^64)
  int offB[4][2];
  #pragma unroll
  for (int nf = 0; nf < 4; ++nf) {
    int row = kw * 64 + nf * 16 + (l & 15);
    int base = row * 128 + (((l >> 4) ^ (row & 7)) * 16);
    offB[nf][0] = base; offB[nf][1] = base ^ 64;
  }
  const int kgb = K0 + kw * 64 + (l & 15);

  // ---- A: one-time direct global->register preload (16 x b8 = 64 VGPR) ----
  b8 ar[4][2][2];                       // [dt][kk][mf]
  {
    const char* ab = (const char*)rb +
        (size_t)(m0 + mw * 32 + (l & 15)) * 512 + (l >> 4) * 16;
    #pragma unroll
    for (int dt = 0; dt < 4; ++dt)
      #pragma unroll
      for (int kk = 0; kk < 2; ++kk)
        #pragma unroll
        for (int mf = 0; mf < 2; ++mf)
          ar[dt][kk][mf] =
              *(const b8*)(ab + mf * (16 * 512) + dt * 128 + kk * 64);
  }
  // ---- cchat slice -> LDS (1024 floats) ----
  if (tid < 256)
    gll16((const char*)cchat + (size_t)K0 * 4 + tid * 16, lds + 65536 + tid * 16);

  asm volatile("s_waitcnt vmcnt(0)");   // ar + cc resident; vmem FIFO clean
  __builtin_amdgcn_sched_barrier(0);

  // prime: stage 0 -> buf0, stage 1 -> buf1 (2 vmem instr per stage per wave)
  #pragma unroll
  for (int it = 0; it < 2; ++it)
    gll16((const char*)cbh + boff[it], lds + ldst[it]);
  #pragma unroll
  for (int it = 0; it < 2; ++it)
    gll16((const char*)cbh + boff[it] + 128, lds + 16384 + ldst[it]);
  asm volatile("s_waitcnt vmcnt(2)");   // own stage-0 loads landed
  __builtin_amdgcn_sched_barrier(0);
  __builtin_amdgcn_s_barrier();         // all waves' stage 0 landed
  __builtin_amdgcn_sched_barrier(0);

  const float* ccl = (const float*)(lds + 65536);

  float tv1[8], tv2[8];
  int   ti1[8];
  #pragma unroll
  for (int s = 0; s < 8; ++s) { tv1[s] = 3.4e38f; tv2[s] = 3.4e38f; ti1[s] = 0; }

  f4 acc[2][4];

  for (int kt = 0; kt < KT; ++kt) {
    #pragma unroll
    for (int dt = 0; dt < 4; ++dt) {
      // a: ds_read this stage's B fragments from buf[dt]
      b8 bb[4][2];
      #pragma unroll
      for (int nf = 0; nf < 4; ++nf)
        #pragma unroll
        for (int kk = 0; kk < 2; ++kk)
          bb[nf][kk] = *(const b8*)(lds + dt * 16384 + offB[nf][kk]);
      // b: issue stage p+2 into buf[(dt+2)&3]  (p = kt*4+dt; valid p<=29)
      if (!(kt == KT - 1 && dt >= 2)) {
        const int skt = (dt >= 2) ? kt + 1 : kt;
        const int sdt = (dt + 2) & 3;
        #pragma unroll
        for (int it = 0; it < 2; ++it)
          gll16((const char*)cbh + boff[it] + skt * 65536 + sdt * 128,
                lds + ((dt + 2) & 3) * 16384 + ldst[it]);
      }
      // c: counted wait — own share of stage p+1 landed (p+2 stays in flight)
      if (!(kt == KT - 1 && dt >= 2)) {
        asm volatile("s_waitcnt vmcnt(2)");
      } else if (dt == 2) {             // p == 30: drain g(31)
        asm volatile("s_waitcnt vmcnt(0)");
      }
      __builtin_amdgcn_sched_barrier(0);
      // d: join — after this, buf[p+1] is complete for every wave
      __builtin_amdgcn_s_barrier();
      __builtin_amdgcn_sched_barrier(0);
      // e: own frag ds_reads complete
      asm volatile("s_waitcnt lgkmcnt(0)");
      __builtin_amdgcn_sched_barrier(0);
      // f: MFMA
      if (dt == 0) {
        #pragma unroll
        for (int i = 0; i < 2; ++i)
          #pragma unroll
          for (int j = 0; j < 4; ++j)
            acc[i][j] = (f4){0.f, 0.f, 0.f, 0.f};
      }
      __builtin_amdgcn_s_setprio(1);
      #pragma unroll
      for (int kk = 0; kk < 2; ++kk)
        #pragma unroll
        for (int mf = 0; mf < 2; ++mf)
          #pragma unroll
          for (int nf = 0; nf < 4; ++nf)
            acc[mf][nf] = __builtin_amdgcn_mfma_f32_16x16x32_bf16(
                ar[dt][kk][mf], bb[nf][kk], acc[mf][nf], 0, 0, 0);
      __builtin_amdgcn_s_setprio(0);
      // g: fold tile kt into running top-2 (med3 form, validated R14/R15)
      if (dt == 3) {
        float cn[4]; int kg[4];
        #pragma unroll
        for (int nf = 0; nf < 4; ++nf) {
          kg[nf] = kgb + kt * 128 + nf * 16;
          cn[nf] = ccl[kt * 128 + kw * 64 + nf * 16 + (l & 15)];
        }
        #pragma unroll
        for (int mf = 0; mf < 2; ++mf)
          #pragma unroll
          for (int r = 0; r < 4; ++r) {
            const int s0 = mf * 4 + r;
            #pragma unroll
            for (int nf = 0; nf < 4; ++nf) {
              float s = fmaf(-2.f, acc[mf][nf][r], cn[nf]);
              bool  c = s < tv1[s0];
              tv2[s0] = __builtin_amdgcn_fmed3f(s, tv1[s0], tv2[s0]);
              ti1[s0] = c ? kg[nf] : ti1[s0];
              tv1[s0] = fminf(tv1[s0], s);
            }
          }
      }
    }
  }
  __syncthreads();                      // full drain before LDS alias reuse

  // ---- single end-of-block reduction (alias lds as merge buffer) ----
  float* Mv1 = (float*)lds;             // [128][2]
  int*   Mi1 = (int*)(lds + 1024);
  float* Mv2 = (float*)(lds + 2048);

  #pragma unroll
  for (int s0 = 0; s0 < 8; ++s0) {
    float v1 = tv1[s0], v2 = tv2[s0];
    int   i1 = ti1[s0];
    #pragma unroll
    for (int m = 1; m < 16; m <<= 1) {
      float qv1 = __shfl_xor(v1, m);
      int   qi1 = __shfl_xor(i1, m);
      float qv2 = __shfl_xor(v2, m);
      bool  qw  = (qv1 < v1) || (qv1 == v1 && qi1 < i1);
      float lose = qw ? v1 : qv1;
      float wv2  = qw ? qv2 : v2;
      v2 = fminf(wv2, lose);
      if (qw) { v1 = qv1; i1 = qi1; }
    }
    if ((l & 15) == 0) {
      int mf = s0 >> 2, r = s0 & 3;
      int rowL = mw * 32 + mf * 16 + (l >> 4) * 4 + r;
      Mv1[rowL * 2 + kw] = v1; Mi1[rowL * 2 + kw] = i1; Mv2[rowL * 2 + kw] = v2;
    }
  }
  __syncthreads();
  if (tid < 128) {
    float a1 = Mv1[tid * 2],     a2 = Mv2[tid * 2];     int a1i = Mi1[tid * 2];
    float b1 = Mv1[tid * 2 + 1], b2 = Mv2[tid * 2 + 1]; int b1i = Mi1[tid * 2 + 1];
    bool  bw = (b1 < a1) || (b1 == a1 && b1i < a1i);
    float v1 = bw ? b1 : a1; int i1 = bw ? b1i : a1i;
    float v2 = fminf(bw ? b2 : a2, bw ? a1 : b1);
    int n = m0 + tid;
    pv1[kblk * NVEC + n] = v1;
    pi1[kblk * NVEC + n] = i1;
    pv2[kblk * NVEC + n] = v2;
  }
}

// ---------------------------------------------------------------------------
// merge: global top2 over KBLK partials; provisional idx; flag near-ties.
// ---------------------------------------------------------------------------
__global__ __launch_bounds__(256) void merge_kernel(
    const float* __restrict__ pv1, const int* __restrict__ pi1,
    const float* __restrict__ pv2, const float* __restrict__ vnorm,
    int* __restrict__ idx, int* __restrict__ flist, int* __restrict__ fslot,
    int* __restrict__ fcount) {
  int n = blockIdx.x * 256 + threadIdx.x;
  float v1 = 3.4e38f, v2 = 3.4e38f; int i1 = 0;
  #pragma unroll
  for (int kb = 0; kb < KBLK; ++kb) {
    float b1 = pv1[kb * NVEC + n]; int b1i = pi1[kb * NVEC + n];
    float b2 = pv2[kb * NVEC + n];
    bool  bw = (b1 < v1) || (b1 == v1 && b1i < i1);
    float lose = bw ? v1 : b1;
    float wv2  = bw ? b2 : v2;
    v2 = fminf(wv2, lose);
    if (bw) { v1 = b1; i1 = b1i; }
  }
  idx[n] = i1;
  float thr = KAPPA * sqrtf(fmaxf(v1 + vnorm[n], 0.f)) + 1e-5f;
  int slot = -1;
  if (v2 - v1 < thr) {
    slot = atomicAdd(fcount, 1);
    flist[slot] = n;
  }
  fslot[n] = slot;
}

// ---------------------------------------------------------------------------
// fb_scan_t: exact f32 rescan for flagged vectors, transposed codebook.
// chunk = FV(8) vectors; grid = FCH(128) chunk-slots x FKS = 4096 blocks.
// ---------------------------------------------------------------------------
__global__ __launch_bounds__(256, 4) void fb_scan_t(
    const float* __restrict__ cbT, const float* __restrict__ cc,
    const float* __restrict__ resid, const int* __restrict__ flist,
    const int* __restrict__ fcount,
    float* __restrict__ fpv, int* __restrict__ fpi) {
  __shared__ float vsT[DIM][FV + 4];       // 48B rows, f4-aligned
  __shared__ float mv[FV][4];
  __shared__ int   mi[FV][4];
  const int cnt = min(*fcount, FCAP);
  const int ks = blockIdx.x & (FKS - 1);
  const int t = threadIdx.x;
  const int w = t >> 6, l = t & 63;
  const int k = ks * 256 + t;
  const float cn = cc[k];

  for (int chunk = blockIdx.x >> 5; chunk * FV < cnt; chunk += FCH) {
    __syncthreads();
    #pragma unroll
    for (int v = 0; v < FV; ++v) {
      int s = chunk * FV + v;
      int n = flist[s < cnt ? s : chunk * FV];
      vsT[t][v] = resid[(size_t)n * DIM + t];
    }
    __syncthreads();

    float dot[FV];
    #pragma unroll
    for (int v = 0; v < FV; ++v) dot[v] = 0.f;

    #pragma unroll 8
    for (int d = 0; d < DIM; ++d) {
      float cv = cbT[(size_t)d * NCODE + k];
      f4 a0 = *(const f4*)&vsT[d][0];
      f4 a1 = *(const f4*)&vsT[d][4];
      dot[0] = fmaf(cv, a0[0], dot[0]);
      dot[1] = fmaf(cv, a0[1], dot[1]);
      dot[2] = fmaf(cv, a0[2], dot[2]);
      dot[3] = fmaf(cv, a0[3], dot[3]);
      dot[4] = fmaf(cv, a1[0], dot[4]);
      dot[5] = fmaf(cv, a1[1], dot[5]);
      dot[6] = fmaf(cv, a1[2], dot[6]);
      dot[7] = fmaf(cv, a1[3], dot[7]);
    }

    #pragma unroll
    for (int v = 0; v < FV; ++v) {
      float bv = fmaf(-2.f, dot[v], cn);
      int   bi = k;
      #pragma unroll
      for (int m = 1; m < 64; m <<= 1) {
        float qv = __shfl_xor(bv, m);
        int   qi = __shfl_xor(bi, m);
        if (qv < bv || (qv == bv && qi < bi)) { bv = qv; bi = qi; }
      }
      if (l == 0) { mv[v][w] = bv; mi[v][w] = bi; }
    }
    __syncthreads();
    if (t < FV) {
      float bv = mv[t][0]; int bi = mi[t][0];
      #pragma unroll
      for (int ww = 1; ww < 4; ++ww) {
        float qv = mv[t][ww]; int qi = mi[t][ww];
        if (qv < bv || (qv == bv && qi < bi)) { bv = qv; bi = qi; }
      }
      if (chunk * FV + t < cnt) {
        fpv[(size_t)(chunk * FV + t) * FKS + ks] = bv;
        fpi[(size_t)(chunk * FV + t) * FKS + ks] = bi;
      }
    }
  }
}

// ---------------------------------------------------------------------------
// update: final idx (inline fb-merge for flagged); resid -= cb[idx];
// rb = bf16(resid); rsum; code out as float. One wave per vector.
// ---------------------------------------------------------------------------
__global__ __launch_bounds__(256) void update_kernel(
    const float* __restrict__ cb, const int* __restrict__ idx,
    const int* __restrict__ fslot,
    const float* __restrict__ fpv, const int* __restrict__ fpi,
    float* __restrict__ resid, unsigned short* __restrict__ rb,
    float* __restrict__ rsum_out, float* __restrict__ codes_out, int depth) {
  int n    = blockIdx.x * 4 + (threadIdx.x >> 6);
  int lane = threadIdx.x & 63;
  int s    = fslot[n];                   // wave-uniform
  int bi;
  if (s >= 0) {
    float v = 3.4e38f; int ii = 0x7fffffff;
    if (lane < FKS) { v = fpv[(size_t)s * FKS + lane]; ii = fpi[(size_t)s * FKS + lane]; }
    #pragma unroll
    for (int m = 1; m < FKS; m <<= 1) {
      float qv = __shfl_xor(v, m);
      int   qi = __shfl_xor(ii, m);
      if (qv < v || (qv == v && qi < ii)) { v = qv; ii = qi; }
    }
    bi = __shfl(ii, 0, 64);
  } else {
    bi = idx[n];
  }
  float4 q = *(const float4*)&cb[(size_t)bi * DIM + lane * 4];
  float4 r = *(float4*)&resid[(size_t)n * DIM + lane * 4];
  r.x -= q.x; r.y -= q.y; r.z -= q.z; r.w -= q.w;
  *(float4*)&resid[(size_t)n * DIM + lane * 4] = r;
  b4 hv; hv[0] = (short)f2bf(r.x); hv[1] = (short)f2bf(r.y);
  hv[2] = (short)f2bf(r.z); hv[3] = (short)f2bf(r.w);
  *(b4*)&rb[(size_t)n * DIM + lane * 4] = hv;
  float s2 = r.x * r.x + r.y * r.y + r.z * r.z + r.w * r.w;
  #pragma unroll
  for (int off = 32; off > 0; off >>= 1) s2 += __shfl_down(s2, off, 64);
  if (lane == 0) {
    rsum_out[n] = s2;
    codes_out[n * DEPTH + depth] = (float)bi;
  }
}

// ---------------------------------------------------------------------------
// finalize: quants = x - resid (in place); block 0 reduces commitment loss.
// ---------------------------------------------------------------------------
__global__ __launch_bounds__(256) void finalize(const float* __restrict__ x,
                                                float* __restrict__ out,
                                                const float* __restrict__ rsumL) {
  int i = blockIdx.x * blockDim.x + threadIdx.x;
  float4 r  = *(float4*)&out[(size_t)i * 4];
  float4 xv = *(const float4*)&x[(size_t)i * 4];
  float4 o;
  o.x = xv.x - r.x; o.y = xv.y - r.y; o.z = xv.z - r.z; o.w = xv.w - r.w;
  *(float4*)&out[(size_t)i * 4] = o;

  if (blockIdx.x == 0) {
    __shared__ float sm[256];
    float s = 0.f;
    for (int j = threadIdx.x; j < DEPTH * NVEC; j += 256) s += rsumL[j];
    sm[threadIdx.x] = s;
    __syncthreads();
    for (int off = 128; off > 0; off >>= 1) {
      if (threadIdx.x < off) sm[threadIdx.x] += sm[threadIdx.x + off];
      __syncthreads();
    }
    if (threadIdx.x == 0)
      out[NVEC * DIM] = sm[0] / (float)DEPTH / (float)(NVEC * DIM);
  }
}

// ---------------------------------------------------------------------------
extern "C" void kernel_launch(void* const* d_in, const int* in_sizes, int n_in,
                              void* d_out, int out_size, void* d_ws, size_t ws_size,
                              hipStream_t stream) {
  const float* x  = (const float*)d_in[0];
  const float* cb = (const float*)d_in[1];
  float* out = (float*)d_out;
  char*  wsb = (char*)d_ws;

  // ws layout (~20 MB, under the proven 22.3 MB)
  unsigned short* cbh = (unsigned short*)(wsb);                 // 4 MB (per-depth)
  unsigned short* rb  = (unsigned short*)(wsb + 4194304);       // 4 MB
  float* cbT   = (float*)(wsb + 8388608);                       // 8 MB (per-depth)
  float* cc    = (float*)(wsb + 16777216);                      // 128 KB
  float* cchat = (float*)(wsb + 16908288);                      // 128 KB
  float* pv1   = (float*)(wsb + 17039360);                      // 512 KB
  int*   pi1   = (int*)  (wsb + 17563648);                      // 512 KB
  float* pv2   = (float*)(wsb + 18087936);                      // 512 KB
  float* rsum  = (float*)(wsb + 18612224);                      // 160 KB
  int*   idx   = (int*)  (wsb + 18776064);                      // 32 KB
  int*   flist = (int*)  (wsb + 18808832);                      // 32 KB
  int*   fslot = (int*)  (wsb + 18841600);                      // 32 KB
  int*   fcount= (int*)  (wsb + 18874368);                      // 4 KB pad
  float* fpv   = (float*)(wsb + 18878464);                      // 1 MB
  int*   fpi   = (int*)  (wsb + 19927040);                      // 1 MB

  float* resid     = out;                    // quants region doubles as resid
  float* codes_out = out + NVEC * DIM + 1;

  prep_norms<<<(DEPTH * NCODE) / 4, 256, 0, stream>>>(cb, cc, cchat);
  init_kernel<<<NVEC / 4, 256, 0, stream>>>(x, resid, rb, rsum);

  for (int d = 0; d < DEPTH; ++d) {
    const size_t cbo = (size_t)d * NCODE * DIM;
    prep_depth<<<512, 256, 0, stream>>>(cb + cbo, cbh, cbT);
    coarse_kernel<<<(NVEC / 128) * KBLK, 512, 0, stream>>>(
        rb, cbh, cchat + d * NCODE, pv1, pi1, pv2, fcount);
    merge_kernel<<<NVEC / 256, 256, 0, stream>>>(
        pv1, pi1, pv2, rsum + d * NVEC, idx, flist, fslot, fcount);
    fb_scan_t<<<FCH * FKS, 256, 0, stream>>>(
        cbT, cc + d * NCODE, resid, flist, fcount, fpv, fpi);
    update_kernel<<<NVEC / 4, 256, 0, stream>>>(
        cb + cbo, idx, fslot, fpv, fpi, resid, rb,
        rsum + (d + 1) * NVEC, codes_out, d);
  }
  finalize<<<(NVEC * DIM / 4) / 256, 256, 0, stream>>>(x, out, rsum + NVEC);
}

// Round 17
// 433.346 us; speedup vs baseline: 2.0139x; 1.0325x over previous
//
#include <hip/hip_runtime.h>

#define DIM   256
#define NVEC  8192
#define NCODE 8192
#define DEPTH 4

#define KBLK  8                  // coarse k-splits; 1024 codes per block
#define KC    (NCODE / KBLK)
#define KT    (KC / 128)         // 8 code-tiles of 128 per block
#define FCAP  8192               // = NVEC: flag list can never overflow
#define FKS   32                 // fallback k-slices (256 codes each)
#define FV    8                  // fallback vectors per chunk
#define FCH   128                // fallback chunk-slots in grid
#define KAPPA 0.018f

typedef short  b8 __attribute__((ext_vector_type(8)));   // 8 bf16 raw
typedef short  b4 __attribute__((ext_vector_type(4)));
typedef float  f4 __attribute__((ext_vector_type(4)));

static __device__ __forceinline__ unsigned short f2bf(float f) {
  unsigned u = __float_as_uint(f);
  return (unsigned short)((u + 0x7FFFu + ((u >> 16) & 1u)) >> 16);  // RNE
}

static __device__ __forceinline__ void gll16(const void* g, void* l) {
  __builtin_amdgcn_global_load_lds(
      (const __attribute__((address_space(1))) void*)g,
      (__attribute__((address_space(3))) void*)l, 16, 0, 0);
}

// ---------------------------------------------------------------------------
// init_kernel: FUSED preprocessing.
// blocks [0, 8192): all-depth code-row norms (true ||c||^2 + bf16 ||ĉ||^2)
// blocks [8192, 10240): resid = x, rb = bf16(x), rsum0 = ||x||^2
// ---------------------------------------------------------------------------
__global__ __launch_bounds__(256) void init_kernel(
    const float* __restrict__ x, float* __restrict__ resid,
    unsigned short* __restrict__ rb, float* __restrict__ rsum0,
    const float* __restrict__ cb_all, float* __restrict__ cc,
    float* __restrict__ cchat) {
  const int lane = threadIdx.x & 63;
  if (blockIdx.x < 8192) {               // norms role
    int row = blockIdx.x * 4 + (threadIdx.x >> 6);
    float4 v = *(const float4*)&cb_all[(size_t)row * DIM + lane * 4];
    float st = 0.f, sh = 0.f;
    float vv[4] = {v.x, v.y, v.z, v.w};
    #pragma unroll
    for (int j = 0; j < 4; ++j) {
      float hf = __uint_as_float(((unsigned)f2bf(vv[j])) << 16);
      st += vv[j] * vv[j];
      sh += hf * hf;
    }
    #pragma unroll
    for (int off = 32; off > 0; off >>= 1) {
      st += __shfl_down(st, off, 64);
      sh += __shfl_down(sh, off, 64);
    }
    if (lane == 0) { cc[row] = st; cchat[row] = sh; }
  } else {                               // init role
    int n = (blockIdx.x - 8192) * 4 + (threadIdx.x >> 6);
    float4 v = *(const float4*)&x[(size_t)n * DIM + lane * 4];
    *(float4*)&resid[(size_t)n * DIM + lane * 4] = v;
    b4 hv; hv[0] = (short)f2bf(v.x); hv[1] = (short)f2bf(v.y);
    hv[2] = (short)f2bf(v.z); hv[3] = (short)f2bf(v.w);
    *(b4*)&rb[(size_t)n * DIM + lane * 4] = hv;
    float s = v.x * v.x + v.y * v.y + v.z * v.z + v.w * v.w;
    #pragma unroll
    for (int off = 32; off > 0; off >>= 1) s += __shfl_down(s, off, 64);
    if (lane == 0) rsum0[n] = s;
  }
}

// ---------------------------------------------------------------------------
// prep_depth: codebook -> bf16 row-major (cbh) + f32 transposed (cbT).
// 512 blocks per depth; depth = blockIdx>>9 (grid 512: single depth;
// grid 2048: all 4 depths in one launch — big-ws fast path).
// ---------------------------------------------------------------------------
__global__ __launch_bounds__(256) void prep_depth(const float* __restrict__ cb,
                                                  unsigned short* __restrict__ cbh,
                                                  float* __restrict__ cbT) {
  __shared__ float ts[64][68];
  const int dep = blockIdx.x >> 9;
  const int bid = blockIdx.x & 511;
  const float* cbd = cb + (size_t)dep * NCODE * DIM;
  unsigned short* cbh_d = cbh + (size_t)dep * NCODE * DIM;
  float* cbT_d = cbT + (size_t)dep * NCODE * DIM;

  const int kb = bid >> 2, db = bid & 3;
  const int k0 = kb * 64, d0 = db * 64;
  const int t  = threadIdx.x;
  const int r  = t >> 2;
  const int c4 = (t & 3) * 16;

  const float* src = cbd + (size_t)(k0 + r) * DIM + d0 + c4;
  float4 q[4];
  #pragma unroll
  for (int i = 0; i < 4; ++i) q[i] = *(const float4*)(src + i * 4);

  b8 h0, h1;
  #pragma unroll
  for (int j = 0; j < 4; ++j) { h0[j] = (short)f2bf(q[0][j]); h0[4 + j] = (short)f2bf(q[1][j]); }
  #pragma unroll
  for (int j = 0; j < 4; ++j) { h1[j] = (short)f2bf(q[2][j]); h1[4 + j] = (short)f2bf(q[3][j]); }
  *(b8*)&cbh_d[(size_t)(k0 + r) * DIM + d0 + c4]     = h0;
  *(b8*)&cbh_d[(size_t)(k0 + r) * DIM + d0 + c4 + 8] = h1;

  #pragma unroll
  for (int i = 0; i < 4; ++i)
    #pragma unroll
    for (int j = 0; j < 4; ++j)
      ts[c4 + i * 4 + j][r] = q[i][j];
  __syncthreads();

  const int dd = t >> 2, kk4 = (t & 3) * 16;
  float* dst = cbT_d + (size_t)(d0 + dd) * NCODE + k0 + kk4;
  #pragma unroll
  for (int q4 = 0; q4 < 4; ++q4)
    *(float4*)(dst + q4 * 4) = *(const float4*)&ts[dd][kk4 + q4 * 4];
}

// ---------------------------------------------------------------------------
// coarse: bf16 MFMA distance GEMM — R16 verbatim (best measured 53.3us):
// fine-interleaved counted-vmcnt pipeline, 4x16KB B ring buffers, depth-2
// gll16 prefetch, vmcnt(2) counted waits, raw s_barrier, sched_barrier
// fences; A one-time global->reg preload; med3 fold; cchat slice in LDS.
// 512 threads = 8 waves as 4x2 (mw,kw); grid = 64 mblk x KBLK.
// ---------------------------------------------------------------------------
__global__ __launch_bounds__(512, 2) void coarse_kernel(
    const unsigned short* __restrict__ rb,
    const unsigned short* __restrict__ cbh,
    const float* __restrict__ cchat,
    float* __restrict__ pv1, int* __restrict__ pi1, float* __restrict__ pv2,
    int* __restrict__ fcount) {
  // B0 @0, B1 @16K, B2 @32K, B3 @48K, cchat @64K (4KB)
  __shared__ __align__(16) char lds[69632];

  const int tid  = threadIdx.x;
  const int w    = tid >> 6;
  const int l    = tid & 63;
  const int mw   = w >> 1, kw = w & 1;          // 4 x 2 wave grid
  const int mblk = blockIdx.x / KBLK;
  const int kblk = blockIdx.x % KBLK;
  const int m0   = mblk * 128;
  const int K0   = kblk * KC;

  if (blockIdx.x == 0 && tid == 0) *fcount = 0;   // merge runs after: race-free

  // B staging: 1024 chunks of 16B per stage, 2 per thread
  int boff[2], ldst[2];
  #pragma unroll
  for (int it = 0; it < 2; ++it) {
    int o = it * 512 + tid;
    int row = o >> 3, ssl = (o & 7) ^ (row & 7);
    boff[it] = (K0 + row) * 512 + ssl * 16;
    ldst[it] = o * 16;
  }
  // B fragment ds_read byte offsets (kk in {0,1} -> ^64)
  int offB[4][2];
  #pragma unroll
  for (int nf = 0; nf < 4; ++nf) {
    int row = kw * 64 + nf * 16 + (l & 15);
    int base = row * 128 + (((l >> 4) ^ (row & 7)) * 16);
    offB[nf][0] = base; offB[nf][1] = base ^ 64;
  }
  const int kgb = K0 + kw * 64 + (l & 15);

  // ---- A: one-time direct global->register preload (16 x b8 = 64 VGPR) ----
  b8 ar[4][2][2];                       // [dt][kk][mf]
  {
    const char* ab = (const char*)rb +
        (size_t)(m0 + mw * 32 + (l & 15)) * 512 + (l >> 4) * 16;
    #pragma unroll
    for (int dt = 0; dt < 4; ++dt)
      #pragma unroll
      for (int kk = 0; kk < 2; ++kk)
        #pragma unroll
        for (int mf = 0; mf < 2; ++mf)
          ar[dt][kk][mf] =
              *(const b8*)(ab + mf * (16 * 512) + dt * 128 + kk * 64);
  }
  // ---- cchat slice -> LDS (1024 floats) ----
  if (tid < 256)
    gll16((const char*)cchat + (size_t)K0 * 4 + tid * 16, lds + 65536 + tid * 16);

  asm volatile("s_waitcnt vmcnt(0)");   // ar + cc resident; vmem FIFO clean
  __builtin_amdgcn_sched_barrier(0);

  // prime: stage 0 -> buf0, stage 1 -> buf1
  #pragma unroll
  for (int it = 0; it < 2; ++it)
    gll16((const char*)cbh + boff[it], lds + ldst[it]);
  #pragma unroll
  for (int it = 0; it < 2; ++it)
    gll16((const char*)cbh + boff[it] + 128, lds + 16384 + ldst[it]);
  asm volatile("s_waitcnt vmcnt(2)");   // own stage-0 loads landed
  __builtin_amdgcn_sched_barrier(0);
  __builtin_amdgcn_s_barrier();         // all waves' stage 0 landed
  __builtin_amdgcn_sched_barrier(0);

  const float* ccl = (const float*)(lds + 65536);

  float tv1[8], tv2[8];
  int   ti1[8];
  #pragma unroll
  for (int s = 0; s < 8; ++s) { tv1[s] = 3.4e38f; tv2[s] = 3.4e38f; ti1[s] = 0; }

  f4 acc[2][4];

  for (int kt = 0; kt < KT; ++kt) {
    #pragma unroll
    for (int dt = 0; dt < 4; ++dt) {
      // a: ds_read this stage's B fragments from buf[dt]
      b8 bb[4][2];
      #pragma unroll
      for (int nf = 0; nf < 4; ++nf)
        #pragma unroll
        for (int kk = 0; kk < 2; ++kk)
          bb[nf][kk] = *(const b8*)(lds + dt * 16384 + offB[nf][kk]);
      // b: issue stage p+2 into buf[(dt+2)&3]  (p = kt*4+dt; valid p<=29)
      if (!(kt == KT - 1 && dt >= 2)) {
        const int skt = (dt >= 2) ? kt + 1 : kt;
        const int sdt = (dt + 2) & 3;
        #pragma unroll
        for (int it = 0; it < 2; ++it)
          gll16((const char*)cbh + boff[it] + skt * 65536 + sdt * 128,
                lds + ((dt + 2) & 3) * 16384 + ldst[it]);
      }
      // c: counted wait — stage p+1 landed (p+2 stays in flight)
      if (!(kt == KT - 1 && dt >= 2)) {
        asm volatile("s_waitcnt vmcnt(2)");
      } else if (dt == 2) {
        asm volatile("s_waitcnt vmcnt(0)");
      }
      __builtin_amdgcn_sched_barrier(0);
      // d: join
      __builtin_amdgcn_s_barrier();
      __builtin_amdgcn_sched_barrier(0);
      // e: own frag ds_reads complete
      asm volatile("s_waitcnt lgkmcnt(0)");
      __builtin_amdgcn_sched_barrier(0);
      // f: MFMA
      if (dt == 0) {
        #pragma unroll
        for (int i = 0; i < 2; ++i)
          #pragma unroll
          for (int j = 0; j < 4; ++j)
            acc[i][j] = (f4){0.f, 0.f, 0.f, 0.f};
      }
      __builtin_amdgcn_s_setprio(1);
      #pragma unroll
      for (int kk = 0; kk < 2; ++kk)
        #pragma unroll
        for (int mf = 0; mf < 2; ++mf)
          #pragma unroll
          for (int nf = 0; nf < 4; ++nf)
            acc[mf][nf] = __builtin_amdgcn_mfma_f32_16x16x32_bf16(
                ar[dt][kk][mf], bb[nf][kk], acc[mf][nf], 0, 0, 0);
      __builtin_amdgcn_s_setprio(0);
      // g: fold tile kt into running top-2 (med3 form)
      if (dt == 3) {
        float cn[4]; int kg[4];
        #pragma unroll
        for (int nf = 0; nf < 4; ++nf) {
          kg[nf] = kgb + kt * 128 + nf * 16;
          cn[nf] = ccl[kt * 128 + kw * 64 + nf * 16 + (l & 15)];
        }
        #pragma unroll
        for (int mf = 0; mf < 2; ++mf)
          #pragma unroll
          for (int r = 0; r < 4; ++r) {
            const int s0 = mf * 4 + r;
            #pragma unroll
            for (int nf = 0; nf < 4; ++nf) {
              float s = fmaf(-2.f, acc[mf][nf][r], cn[nf]);
              bool  c = s < tv1[s0];
              tv2[s0] = __builtin_amdgcn_fmed3f(s, tv1[s0], tv2[s0]);
              ti1[s0] = c ? kg[nf] : ti1[s0];
              tv1[s0] = fminf(tv1[s0], s);
            }
          }
      }
    }
  }
  __syncthreads();                      // full drain before LDS alias reuse

  // ---- single end-of-block reduction (alias lds as merge buffer) ----
  float* Mv1 = (float*)lds;             // [128][2]
  int*   Mi1 = (int*)(lds + 1024);
  float* Mv2 = (float*)(lds + 2048);

  #pragma unroll
  for (int s0 = 0; s0 < 8; ++s0) {
    float v1 = tv1[s0], v2 = tv2[s0];
    int   i1 = ti1[s0];
    #pragma unroll
    for (int m = 1; m < 16; m <<= 1) {
      float qv1 = __shfl_xor(v1, m);
      int   qi1 = __shfl_xor(i1, m);
      float qv2 = __shfl_xor(v2, m);
      bool  qw  = (qv1 < v1) || (qv1 == v1 && qi1 < i1);
      float lose = qw ? v1 : qv1;
      float wv2  = qw ? qv2 : v2;
      v2 = fminf(wv2, lose);
      if (qw) { v1 = qv1; i1 = qi1; }
    }
    if ((l & 15) == 0) {
      int mf = s0 >> 2, r = s0 & 3;
      int rowL = mw * 32 + mf * 16 + (l >> 4) * 4 + r;
      Mv1[rowL * 2 + kw] = v1; Mi1[rowL * 2 + kw] = i1; Mv2[rowL * 2 + kw] = v2;
    }
  }
  __syncthreads();
  if (tid < 128) {
    float a1 = Mv1[tid * 2],     a2 = Mv2[tid * 2];     int a1i = Mi1[tid * 2];
    float b1 = Mv1[tid * 2 + 1], b2 = Mv2[tid * 2 + 1]; int b1i = Mi1[tid * 2 + 1];
    bool  bw = (b1 < a1) || (b1 == a1 && b1i < a1i);
    float v1 = bw ? b1 : a1; int i1 = bw ? b1i : a1i;
    float v2 = fminf(bw ? b2 : a2, bw ? a1 : b1);
    int n = m0 + tid;
    pv1[kblk * NVEC + n] = v1;
    pi1[kblk * NVEC + n] = i1;
    pv2[kblk * NVEC + n] = v2;
  }
}

// ---------------------------------------------------------------------------
// merge: global top2 over KBLK partials; provisional idx; flag near-ties.
// ---------------------------------------------------------------------------
__global__ __launch_bounds__(256) void merge_kernel(
    const float* __restrict__ pv1, const int* __restrict__ pi1,
    const float* __restrict__ pv2, const float* __restrict__ vnorm,
    int* __restrict__ idx, int* __restrict__ flist, int* __restrict__ fslot,
    int* __restrict__ fcount) {
  int n = blockIdx.x * 256 + threadIdx.x;
  float v1 = 3.4e38f, v2 = 3.4e38f; int i1 = 0;
  #pragma unroll
  for (int kb = 0; kb < KBLK; ++kb) {
    float b1 = pv1[kb * NVEC + n]; int b1i = pi1[kb * NVEC + n];
    float b2 = pv2[kb * NVEC + n];
    bool  bw = (b1 < v1) || (b1 == v1 && b1i < i1);
    float lose = bw ? v1 : b1;
    float wv2  = bw ? b2 : v2;
    v2 = fminf(wv2, lose);
    if (bw) { v1 = b1; i1 = b1i; }
  }
  idx[n] = i1;
  float thr = KAPPA * sqrtf(fmaxf(v1 + vnorm[n], 0.f)) + 1e-5f;
  int slot = -1;
  if (v2 - v1 < thr) {
    slot = atomicAdd(fcount, 1);
    flist[slot] = n;
  }
  fslot[n] = slot;
}

// ---------------------------------------------------------------------------
// fb_scan_t: exact f32 rescan for flagged vectors, transposed codebook.
// chunk = FV(8) vectors; grid = FCH(128) chunk-slots x FKS = 4096 blocks.
// ---------------------------------------------------------------------------
__global__ __launch_bounds__(256, 4) void fb_scan_t(
    const float* __restrict__ cbT, const float* __restrict__ cc,
    const float* __restrict__ resid, const int* __restrict__ flist,
    const int* __restrict__ fcount,
    float* __restrict__ fpv, int* __restrict__ fpi) {
  __shared__ float vsT[DIM][FV + 4];       // 48B rows, f4-aligned
  __shared__ float mv[FV][4];
  __shared__ int   mi[FV][4];
  const int cnt = min(*fcount, FCAP);
  const int ks = blockIdx.x & (FKS - 1);
  const int t = threadIdx.x;
  const int w = t >> 6, l = t & 63;
  const int k = ks * 256 + t;
  const float cn = cc[k];

  for (int chunk = blockIdx.x >> 5; chunk * FV < cnt; chunk += FCH) {
    __syncthreads();
    #pragma unroll
    for (int v = 0; v < FV; ++v) {
      int s = chunk * FV + v;
      int n = flist[s < cnt ? s : chunk * FV];
      vsT[t][v] = resid[(size_t)n * DIM + t];
    }
    __syncthreads();

    float dot[FV];
    #pragma unroll
    for (int v = 0; v < FV; ++v) dot[v] = 0.f;

    #pragma unroll 8
    for (int d = 0; d < DIM; ++d) {
      float cv = cbT[(size_t)d * NCODE + k];
      f4 a0 = *(const f4*)&vsT[d][0];
      f4 a1 = *(const f4*)&vsT[d][4];
      dot[0] = fmaf(cv, a0[0], dot[0]);
      dot[1] = fmaf(cv, a0[1], dot[1]);
      dot[2] = fmaf(cv, a0[2], dot[2]);
      dot[3] = fmaf(cv, a0[3], dot[3]);
      dot[4] = fmaf(cv, a1[0], dot[4]);
      dot[5] = fmaf(cv, a1[1], dot[5]);
      dot[6] = fmaf(cv, a1[2], dot[6]);
      dot[7] = fmaf(cv, a1[3], dot[7]);
    }

    #pragma unroll
    for (int v = 0; v < FV; ++v) {
      float bv = fmaf(-2.f, dot[v], cn);
      int   bi = k;
      #pragma unroll
      for (int m = 1; m < 64; m <<= 1) {
        float qv = __shfl_xor(bv, m);
        int   qi = __shfl_xor(bi, m);
        if (qv < bv || (qv == bv && qi < bi)) { bv = qv; bi = qi; }
      }
      if (l == 0) { mv[v][w] = bv; mi[v][w] = bi; }
    }
    __syncthreads();
    if (t < FV) {
      float bv = mv[t][0]; int bi = mi[t][0];
      #pragma unroll
      for (int ww = 1; ww < 4; ++ww) {
        float qv = mv[t][ww]; int qi = mi[t][ww];
        if (qv < bv || (qv == bv && qi < bi)) { bv = qv; bi = qi; }
      }
      if (chunk * FV + t < cnt) {
        fpv[(size_t)(chunk * FV + t) * FKS + ks] = bv;
        fpi[(size_t)(chunk * FV + t) * FKS + ks] = bi;
      }
    }
  }
}

// ---------------------------------------------------------------------------
// update: final idx (inline fb-merge for flagged); resid -= cb[idx];
// rb = bf16(resid); rsum; code out as float. One wave per vector.
// ---------------------------------------------------------------------------
__global__ __launch_bounds__(256) void update_kernel(
    const float* __restrict__ cb, const int* __restrict__ idx,
    const int* __restrict__ fslot,
    const float* __restrict__ fpv, const int* __restrict__ fpi,
    float* __restrict__ resid, unsigned short* __restrict__ rb,
    float* __restrict__ rsum_out, float* __restrict__ codes_out, int depth) {
  int n    = blockIdx.x * 4 + (threadIdx.x >> 6);
  int lane = threadIdx.x & 63;
  int s    = fslot[n];                   // wave-uniform
  int bi;
  if (s >= 0) {
    float v = 3.4e38f; int ii = 0x7fffffff;
    if (lane < FKS) { v = fpv[(size_t)s * FKS + lane]; ii = fpi[(size_t)s * FKS + lane]; }
    #pragma unroll
    for (int m = 1; m < FKS; m <<= 1) {
      float qv = __shfl_xor(v, m);
      int   qi = __shfl_xor(ii, m);
      if (qv < v || (qv == v && qi < ii)) { v = qv; ii = qi; }
    }
    bi = __shfl(ii, 0, 64);
  } else {
    bi = idx[n];
  }
  float4 q = *(const float4*)&cb[(size_t)bi * DIM + lane * 4];
  float4 r = *(float4*)&resid[(size_t)n * DIM + lane * 4];
  r.x -= q.x; r.y -= q.y; r.z -= q.z; r.w -= q.w;
  *(float4*)&resid[(size_t)n * DIM + lane * 4] = r;
  b4 hv; hv[0] = (short)f2bf(r.x); hv[1] = (short)f2bf(r.y);
  hv[2] = (short)f2bf(r.z); hv[3] = (short)f2bf(r.w);
  *(b4*)&rb[(size_t)n * DIM + lane * 4] = hv;
  float s2 = r.x * r.x + r.y * r.y + r.z * r.z + r.w * r.w;
  #pragma unroll
  for (int off = 32; off > 0; off >>= 1) s2 += __shfl_down(s2, off, 64);
  if (lane == 0) {
    rsum_out[n] = s2;
    codes_out[n * DEPTH + depth] = (float)bi;
  }
}

// ---------------------------------------------------------------------------
// finalize: quants = x - resid (in place); block 0 reduces commitment loss.
// ---------------------------------------------------------------------------
__global__ __launch_bounds__(256) void finalize(const float* __restrict__ x,
                                                float* __restrict__ out,
                                                const float* __restrict__ rsumL) {
  int i = blockIdx.x * blockDim.x + threadIdx.x;
  float4 r  = *(float4*)&out[(size_t)i * 4];
  float4 xv = *(const float4*)&x[(size_t)i * 4];
  float4 o;
  o.x = xv.x - r.x; o.y = xv.y - r.y; o.z = xv.z - r.z; o.w = xv.w - r.w;
  *(float4*)&out[(size_t)i * 4] = o;

  if (blockIdx.x == 0) {
    __shared__ float sm[256];
    float s = 0.f;
    for (int j = threadIdx.x; j < DEPTH * NVEC; j += 256) s += rsumL[j];
    sm[threadIdx.x] = s;
    __syncthreads();
    for (int off = 128; off > 0; off >>= 1) {
      if (threadIdx.x < off) sm[threadIdx.x] += sm[threadIdx.x + off];
      __syncthreads();
    }
    if (threadIdx.x == 0)
      out[NVEC * DIM] = sm[0] / (float)DEPTH / (float)(NVEC * DIM);
  }
}

// ---------------------------------------------------------------------------
extern "C" void kernel_launch(void* const* d_in, const int* in_sizes, int n_in,
                              void* d_out, int out_size, void* d_ws, size_t ws_size,
                              hipStream_t stream) {
  const float* x  = (const float*)d_in[0];
  const float* cb = (const float*)d_in[1];
  float* out = (float*)d_out;
  char*  wsb = (char*)d_ws;

  // big-ws fast path: all-depth cbh (16MB) + cbT (32MB) precomputed once.
  const bool big = ws_size >= 57937920u;

  unsigned short* cbh;   // per-depth stride NCODE*DIM when big
  float*          cbT;
  unsigned short* rb;
  size_t sb;             // small-buffer base offset
  if (big) {
    cbh = (unsigned short*)(wsb);                  // 16 MB (all depths)
    cbT = (float*)(wsb + 16777216);                // 32 MB (all depths)
    rb  = (unsigned short*)(wsb + 50331648);       // 4 MB
    sb  = 54525952;
  } else {
    cbh = (unsigned short*)(wsb);                  // 4 MB (reused per depth)
    rb  = (unsigned short*)(wsb + 4194304);        // 4 MB
    cbT = (float*)(wsb + 8388608);                 // 8 MB (reused per depth)
    sb  = 16777216;
  }
  float* cc    = (float*)(wsb + sb);                       // 128 KB
  float* cchat = (float*)(wsb + sb + 131072);              // 128 KB
  float* pv1   = (float*)(wsb + sb + 262144);              // 256 KB
  int*   pi1   = (int*)  (wsb + sb + 524288);              // 256 KB
  float* pv2   = (float*)(wsb + sb + 786432);              // 256 KB
  float* rsum  = (float*)(wsb + sb + 1048576);             // 160 KB
  int*   idx   = (int*)  (wsb + sb + 1212416);             // 32 KB
  int*   flist = (int*)  (wsb + sb + 1245184);             // 32 KB
  int*   fslot = (int*)  (wsb + sb + 1277952);             // 32 KB
  int*   fcount= (int*)  (wsb + sb + 1310720);             // 4 KB
  float* fpv   = (float*)(wsb + sb + 1314816);             // 1 MB
  int*   fpi   = (int*)  (wsb + sb + 2363392);             // 1 MB

  float* resid     = out;                    // quants region doubles as resid
  float* codes_out = out + NVEC * DIM + 1;

  // fused norms + init (one launch)
  init_kernel<<<10240, 256, 0, stream>>>(x, resid, rb, rsum, cb, cc, cchat);
  if (big)
    prep_depth<<<2048, 256, 0, stream>>>(cb, cbh, cbT);   // all 4 depths

  for (int d = 0; d < DEPTH; ++d) {
    const size_t cbo = (size_t)d * NCODE * DIM;
    unsigned short* cbh_d = big ? cbh + cbo : cbh;
    float*          cbT_d = big ? cbT + cbo : cbT;
    if (!big)
      prep_depth<<<512, 256, 0, stream>>>(cb + cbo, cbh, cbT);
    coarse_kernel<<<(NVEC / 128) * KBLK, 512, 0, stream>>>(
        rb, cbh_d, cchat + d * NCODE, pv1, pi1, pv2, fcount);
    merge_kernel<<<NVEC / 256, 256, 0, stream>>>(
        pv1, pi1, pv2, rsum + d * NVEC, idx, flist, fslot, fcount);
    fb_scan_t<<<FCH * FKS, 256, 0, stream>>>(
        cbT_d, cc + d * NCODE, resid, flist, fcount, fpv, fpi);
    update_kernel<<<NVEC / 4, 256, 0, stream>>>(
        cb + cbo, idx, fslot, fpv, fpi, resid, rb,
        rsum + (d + 1) * NVEC, codes_out, d);
  }
  finalize<<<(NVEC * DIM / 4) / 256, 256, 0, stream>>>(x, out, rsum + NVEC);
}